// Round 1
// baseline (7952.646 us; speedup 1.0000x reference)
//
#include <hip/hip_runtime.h>
#include <math.h>

#define NN 512
#define NP 20000
#define DD 128
#define NH 24
#define G3 384
#define NHD 3072  /* NH*DD */

__device__ __forceinline__ float sigf(float x){ return 1.f/(1.f+expf(-x)); }

/* ---------------- init ---------------- */
__global__ void k_init_ns(float* ns, const float* qp, const float* w1, const float* w2,
                          const float* w3, const float* qs){
  int n = blockIdx.x, c = threadIdx.x;
  float v = 0.f;
  if (c==0) v=qp[n]; else if (c==1) v=w1[n]; else if (c==2) v=w2[n]; else if (c==3) v=w3[n];
  else if (c<7) v=qs[n*3 + (c-4)];
  ns[n*DD+c]=v;
}

__global__ void k_init_ps(float* ps, const float* bw, const float* tos){
  int i = blockIdx.x*256 + threadIdx.x;
  if (i >= NP*DD) return;
  int p = i>>7, c = i&127;
  float v=0.f; if(c==0) v=bw[p]; else if(c==1) v=tos[p];
  ps[i]=v;
}

__global__ void k_adj(float* adjm, const int* idx, const float* lc){
  int l = blockIdx.x*256+threadIdx.x; if(l>=4096) return;
  adjm[idx[l]] = (lc[l]!=0.f)?1.f:0.f;
}

__global__ void k_meta(const int* paths, const int* seqs, int* start, int* lens, int E){
  int e = blockIdx.x*256+threadIdx.x; if(e>=E) return;
  int p=paths[e], s=seqs[e];
  if (s==0) start[p]=e;
  if (e==E-1 || paths[e+1]!=p) lens[p]=s+1;
}

__global__ void k_count(const int* nodes, int* counts, int E){
  int e = blockIdx.x*256+threadIdx.x; if(e>=E) return;
  atomicAdd(&counts[nodes[e]],1);
}

__global__ void k_scan(const int* counts, int* offsets, int* cursor){
  __shared__ int sh[NN];
  int t=threadIdx.x; int v=counts[t]; sh[t]=v; __syncthreads();
  for (int d=1; d<NN; d<<=1){
    int u = (t>=d)? sh[t-d] : 0;
    __syncthreads();
    sh[t]+=u;
    __syncthreads();
  }
  int ex = sh[t]-v;
  offsets[t]=ex; cursor[t]=ex;
}

__global__ void k_fill(const int* nodes, int* cursor, int* bucket, int E){
  int e = blockIdx.x*256+threadIdx.x; if(e>=E) return;
  int pos = atomicAdd(&cursor[nodes[e]],1);
  bucket[pos]=e;
}

/* ---------------- GAT ---------------- */
/* xp[n][h][c] = sum_k ns[n][k] * W[k][h*128+c]; tile 16 rows x 64 cols */
__global__ __launch_bounds__(256) void k_xp(const float* __restrict__ ns,
                                            const float* __restrict__ W,
                                            float* __restrict__ xp){
  __shared__ float A[16][130];
  int r0 = blockIdx.x*16, c0 = blockIdx.y*64;
  int tid = threadIdx.x;
  for (int idx=tid; idx<16*128; idx+=256){ int r=idx>>7,k=idx&127; A[r][k]=ns[(r0+r)*DD+k]; }
  __syncthreads();
  int cc = c0 + (tid&63); int rq = tid>>6;
  float a0=0.f,a1=0.f,a2=0.f,a3=0.f;
  for (int k=0;k<128;k++){
    float b = W[(size_t)k*NHD + cc];
    a0 += A[rq*4+0][k]*b; a1 += A[rq*4+1][k]*b; a2 += A[rq*4+2][k]*b; a3 += A[rq*4+3][k]*b;
  }
  xp[(size_t)(r0+rq*4+0)*NHD+cc]=a0;
  xp[(size_t)(r0+rq*4+1)*NHD+cc]=a1;
  xp[(size_t)(r0+rq*4+2)*NHD+cc]=a2;
  xp[(size_t)(r0+rq*4+3)*NHD+cc]=a3;
}

__global__ void k_gat_e(const float* __restrict__ xp, const float* __restrict__ as_,
                        const float* __restrict__ an_, float* es, float* en){
  int n = blockIdx.x, h = blockIdx.y, t = threadIdx.x; /* 64 threads */
  const float* xr = xp + ((size_t)n*NH + h)*DD;
  const float* ar = as_ + h*DD; const float* br = an_ + h*DD;
  float s1 = xr[t]*ar[t] + xr[t+64]*ar[t+64];
  float s2 = xr[t]*br[t] + xr[t+64]*br[t+64];
  for (int o=32;o>0;o>>=1){ s1 += __shfl_down(s1,o); s2 += __shfl_down(s2,o); }
  if (t==0){ es[n*NH+h]=s1; en[n*NH+h]=s2; }
}

__global__ void k_gat_bias(float* gout, const float* gb){
  int n = blockIdx.x, c = threadIdx.x;
  gout[n*DD+c] = gb[c];
}

__global__ __launch_bounds__(256) void k_attn(const float* __restrict__ xp,
                      const float* __restrict__ es, const float* __restrict__ en,
                      const float* __restrict__ adjm, float* __restrict__ gout){
  __shared__ float lg[32][513];
  __shared__ float mxs[32], isms[32];
  int h = blockIdx.x, it = blockIdx.y; int i0 = it*32; int tid = threadIdx.x;
  /* phase1: logits */
  for (int idx=tid; idx<32*512; idx+=256){
    int ii = idx>>9, j = idx&511;
    float l = es[(i0+ii)*NH+h] + en[j*NH+h];
    l = (l>=0.f)? l : 0.2f*l;
    if (adjm[(size_t)(i0+ii)*NN + j]==0.f) l = -1000000000.0f;
    lg[ii][j] = l;
  }
  __syncthreads();
  /* phase2: max & sum per row (8 threads per ii) */
  {
    int t8 = tid&7, ii = tid>>3;
    float m = -INFINITY;
    for (int j=t8;j<512;j+=8) m = fmaxf(m, lg[ii][j]);
    for (int o=4;o>0;o>>=1) m = fmaxf(m, __shfl_xor(m, o));
    float s=0.f;
    for (int j=t8;j<512;j+=8) s += expf(lg[ii][j]-m);
    for (int o=4;o>0;o>>=1) s += __shfl_xor(s,o);
    if (t8==0){ mxs[ii]=m; isms[ii]=1.f/s; }
  }
  __syncthreads();
  /* phase2.5: overwrite with attn prob */
  for (int idx=tid; idx<32*512; idx+=256){
    int ii = idx>>9, j = idx&511;
    lg[ii][j] = expf(lg[ii][j]-mxs[ii])*isms[ii];
  }
  __syncthreads();
  /* phase3: out[i][c] += sum_j p * xp[j][h][c] */
  int cq = tid&31, iq = tid>>5; int c = cq*4;
  float4 acc0=make_float4(0,0,0,0), acc1=acc0, acc2=acc0, acc3=acc0;
  for (int j=0;j<512;j++){
    const float4 xv = *(const float4*)(xp + ((size_t)j*NH + h)*DD + c);
    float p0 = lg[iq*4+0][j], p1 = lg[iq*4+1][j], p2 = lg[iq*4+2][j], p3 = lg[iq*4+3][j];
    acc0.x+=p0*xv.x; acc0.y+=p0*xv.y; acc0.z+=p0*xv.z; acc0.w+=p0*xv.w;
    acc1.x+=p1*xv.x; acc1.y+=p1*xv.y; acc1.z+=p1*xv.z; acc1.w+=p1*xv.w;
    acc2.x+=p2*xv.x; acc2.y+=p2*xv.y; acc2.z+=p2*xv.z; acc2.w+=p2*xv.w;
    acc3.x+=p3*xv.x; acc3.y+=p3*xv.y; acc3.z+=p3*xv.z; acc3.w+=p3*xv.w;
  }
  const float inv = 1.f/24.f;
  float* o0 = gout + (size_t)(i0+iq*4+0)*DD + c;
  float* o1 = gout + (size_t)(i0+iq*4+1)*DD + c;
  float* o2 = gout + (size_t)(i0+iq*4+2)*DD + c;
  float* o3 = gout + (size_t)(i0+iq*4+3)*DD + c;
  atomicAdd(o0+0,acc0.x*inv); atomicAdd(o0+1,acc0.y*inv); atomicAdd(o0+2,acc0.z*inv); atomicAdd(o0+3,acc0.w*inv);
  atomicAdd(o1+0,acc1.x*inv); atomicAdd(o1+1,acc1.y*inv); atomicAdd(o1+2,acc1.z*inv); atomicAdd(o1+3,acc1.w*inv);
  atomicAdd(o2+0,acc2.x*inv); atomicAdd(o2+1,acc2.y*inv); atomicAdd(o2+2,acc2.z*inv); atomicAdd(o2+3,acc2.w*inv);
  atomicAdd(o3+0,acc3.x*inv); atomicAdd(o3+1,acc3.y*inv); atomicAdd(o3+2,acc3.z*inv); atomicAdd(o3+3,acc3.w*inv);
}

/* xg[n][j] = b0[j] + sum_k gout[n][k]*W[k][j]   grid (512,3), 128 threads */
__global__ void k_xg(const float* __restrict__ gout, const float* __restrict__ W,
                     const float* __restrict__ b0, float* __restrict__ out){
  int n = blockIdx.x; int j = blockIdx.y*128 + threadIdx.x;
  const float* g = gout + (size_t)n*DD;
  float acc = b0[j];
  for (int k=0;k<128;k++) acc += g[k]*W[(size_t)k*G3 + j];
  out[(size_t)n*G3+j] = acc;
}

/* ---------------- path GRU ---------------- */
#define GRUFMA(q) { \
  float4 uz = *(const float4*)(Ur + (q)*4); \
  float4 urr = *(const float4*)(Ur + 128 + (q)*4); \
  float4 uh = *(const float4*)(Ur + 256 + (q)*4); \
  az[(q)*4+0]+=hk*uz.x; az[(q)*4+1]+=hk*uz.y; az[(q)*4+2]+=hk*uz.z; az[(q)*4+3]+=hk*uz.w; \
  ar[(q)*4+0]+=hk*urr.x; ar[(q)*4+1]+=hk*urr.y; ar[(q)*4+2]+=hk*urr.z; ar[(q)*4+3]+=hk*urr.w; \
  ah[(q)*4+0]+=hk*uh.x; ah[(q)*4+1]+=hk*uh.y; ah[(q)*4+2]+=hk*uh.z; ah[(q)*4+3]+=hk*uh.w; }

__global__ __launch_bounds__(256) void k_gru(const float* __restrict__ ps_in,
    float* __restrict__ ps_out,
    const float* __restrict__ xg, const float* __restrict__ U,
    const float* __restrict__ b1,
    const int* __restrict__ start, const int* __restrict__ lens,
    const int* __restrict__ nodes, float* __restrict__ outbuf, int reverse)
{
  __shared__ float Hs[32][129];
  __shared__ int Ls[32], Ss[32];
  int pb = blockIdx.x*32;
  int tid = threadIdx.x;
  int p = tid & 31, g = tid >> 5;
  int c0 = g*16;
  for (int idx=tid; idx<32*128; idx+=256){ int pp=idx>>7,kk=idx&127; Hs[pp][kk]=ps_in[(size_t)(pb+pp)*DD+kk]; }
  if (tid<32){ Ls[tid]=lens[pb+tid]; Ss[tid]=start[pb+tid]; }
  __syncthreads();
  int L = Ls[p], S = Ss[p];
  for (int s=0;s<8;s++){
    float hnew[16];
    bool act = (s < L);
    int e = 0;
    if (act){
      int pos = reverse ? (L-1-s) : s;
      e = S + pos;
      float az[16], ar[16], ah[16];
      #pragma unroll
      for (int i=0;i<16;i++){ az[i]=0.f; ar[i]=0.f; ah[i]=0.f; }
      for (int k=0;k<128;k++){
        float hk = Hs[p][k];
        const float* Ur = U + (size_t)k*G3 + c0;
        GRUFMA(0) GRUFMA(1) GRUFMA(2) GRUFMA(3)
      }
      int nid = nodes[e];
      const float* xr = xg + (size_t)nid*G3;
      #pragma unroll
      for (int i=0;i<16;i++){
        int c = c0+i;
        float z = sigf(xr[c]     + az[i] + b1[c]);
        float r = sigf(xr[128+c] + ar[i] + b1[128+c]);
        float hc = tanhf(xr[256+c] + r*(ah[i] + b1[256+c]));
        hnew[i] = z*Hs[p][c] + (1.f-z)*hc;
      }
    }
    __syncthreads();  /* all reads of old H done */
    if (act){
      #pragma unroll
      for (int i=0;i<16;i++) Hs[p][c0+i] = hnew[i];
      float* o = outbuf + (size_t)e*DD + c0;
      if (!reverse){
        #pragma unroll
        for (int q=0;q<4;q++)
          *(float4*)(o+q*4) = make_float4(hnew[q*4],hnew[q*4+1],hnew[q*4+2],hnew[q*4+3]);
      } else {
        #pragma unroll
        for (int q=0;q<4;q++){
          float4 v = *(float4*)(o+q*4);
          v.x+=hnew[q*4]; v.y+=hnew[q*4+1]; v.z+=hnew[q*4+2]; v.w+=hnew[q*4+3];
          *(float4*)(o+q*4)=v;
        }
      }
    }
    __syncthreads();  /* H update visible before next step */
  }
  if (ps_out){
    for (int idx=tid; idx<32*128; idx+=256){ int pp=idx>>7,kk=idx&127; ps_out[(size_t)(pb+pp)*DD+kk]=Hs[pp][kk]; }
  }
}

/* ---------------- m2 + node GRU ---------------- */
__global__ void k_m2(const float* __restrict__ outbuf, const int* __restrict__ counts,
                     const int* __restrict__ offsets, const int* __restrict__ bucket,
                     float* __restrict__ m2){
  int n = blockIdx.x; int c = threadIdx.x; /* 128 threads */
  int cnt = counts[n], off = offsets[n];
  float acc = 0.f;
  for (int idx=0; idx<cnt; ++idx){
    int e = bucket[off+idx];
    acc += outbuf[(size_t)e*DD + c];
  }
  m2[n*DD+c] = acc;
}

__global__ void k_ngru(const float* __restrict__ m2, const float* __restrict__ gout,
                       const float* __restrict__ Wn, const float* __restrict__ Un,
                       const float* __restrict__ bn, float* __restrict__ ns){
  int n = blockIdx.x, c = threadIdx.x; /* 128 threads */
  float xz=0.f,xr=0.f,xh=0.f,hz=0.f,hr=0.f,hh=0.f;
  const float* x = m2 + (size_t)n*DD; const float* h = gout + (size_t)n*DD;
  for (int k=0;k<128;k++){
    float xk=x[k], hk=h[k];
    const float* wr = Wn + (size_t)k*G3; const float* ur = Un + (size_t)k*G3;
    xz += xk*wr[c]; xr += xk*wr[128+c]; xh += xk*wr[256+c];
    hz += hk*ur[c]; hr += hk*ur[128+c]; hh += hk*ur[256+c];
  }
  float z = sigf(xz+bn[c]     + hz+bn[G3+c]);
  float r = sigf(xr+bn[128+c] + hr+bn[G3+128+c]);
  float hc = tanhf(xh+bn[256+c] + r*(hh+bn[G3+256+c]));
  ns[n*DD+c] = z*h[c] + (1.f-z)*hc;
}

/* ---------------- readout ---------------- */
#define RFMA(q) { float4 w_ = *(const float4*)(wr+(q)*4); \
  acc[(q)*4+0]+=pk*w_.x; acc[(q)*4+1]+=pk*w_.y; acc[(q)*4+2]+=pk*w_.z; acc[(q)*4+3]+=pk*w_.w; }

__global__ __launch_bounds__(256) void k_read(const float* __restrict__ ps,
    const float* __restrict__ rW1, const float* __restrict__ rb1,
    const float* __restrict__ rW2, const float* __restrict__ rb2,
    const float* __restrict__ rW3, const float* __restrict__ rb3, float* __restrict__ out)
{
  __shared__ float psl[16][129];
  __shared__ float h1l[16][257];
  __shared__ float h2l[16][257];
  __shared__ float red[16][17];
  int pb = blockIdx.x*16; int tid = threadIdx.x;
  int p = tid&15, cg = tid>>4; /* cg 0..15 */
  for (int idx=tid; idx<16*128; idx+=256){ int pp=idx>>7,k=idx&127; psl[pp][k]=ps[(size_t)(pb+pp)*DD+k]; }
  __syncthreads();
  /* layer1: selu(ps @ rW1 + rb1), 256-wide */
  {
    float acc[16];
    #pragma unroll
    for (int i=0;i<16;i++) acc[i]=rb1[cg*16+i];
    for (int k=0;k<128;k++){
      float pk = psl[p][k];
      const float* wr = rW1 + (size_t)k*256 + cg*16;
      RFMA(0) RFMA(1) RFMA(2) RFMA(3)
    }
    #pragma unroll
    for (int i=0;i<16;i++){
      float x = acc[i];
      h1l[p][cg*16+i] = 1.0507009873554805f * (x>0.f ? x : 1.6732632423543772f*expm1f(x));
    }
  }
  __syncthreads();
  /* layer2: relu(h1 @ rW2 + rb2) */
  {
    float acc[16];
    #pragma unroll
    for (int i=0;i<16;i++) acc[i]=rb2[cg*16+i];
    for (int k=0;k<256;k++){
      float pk = h1l[p][k];
      const float* wr = rW2 + (size_t)k*256 + cg*16;
      RFMA(0) RFMA(1) RFMA(2) RFMA(3)
    }
    #pragma unroll
    for (int i=0;i<16;i++) h2l[p][cg*16+i] = fmaxf(acc[i],0.f);
  }
  __syncthreads();
  /* layer3 */
  float s=0.f;
  #pragma unroll
  for (int i=0;i<16;i++) s += h2l[p][cg*16+i]*rW3[cg*16+i];
  red[p][cg]=s; __syncthreads();
  if (tid<16){
    float t=rb3[0];
    for (int q=0;q<16;q++) t += red[tid][q];
    out[pb+tid]=t;
  }
}

/* ---------------- host ---------------- */
extern "C" void kernel_launch(void* const* d_in, const int* in_sizes, int n_in,
                              void* d_out, int out_size, void* d_ws, size_t ws_size,
                              hipStream_t stream)
{
  const float* ToS   = (const float*)d_in[0];
  const float* bw    = (const float*)d_in[1];
  const float* qpol  = (const float*)d_in[2];
  const float* w1    = (const float*)d_in[3];
  const float* w2    = (const float*)d_in[4];
  const float* w3    = (const float*)d_in[5];
  const float* qs    = (const float*)d_in[6];
  const float* lc    = (const float*)d_in[7];
  const float* gat_W = (const float*)d_in[8];
  const float* gat_as= (const float*)d_in[9];
  const float* gat_an= (const float*)d_in[10];
  const float* gat_b = (const float*)d_in[11];
  const float* Wp    = (const float*)d_in[12];
  const float* Up    = (const float*)d_in[13];
  const float* bp    = (const float*)d_in[14];
  const float* Wb    = (const float*)d_in[15];
  const float* Ub    = (const float*)d_in[16];
  const float* bb    = (const float*)d_in[17];
  const float* Wn    = (const float*)d_in[18];
  const float* Un    = (const float*)d_in[19];
  const float* bn    = (const float*)d_in[20];
  const float* rW1   = (const float*)d_in[21];
  const float* rb1   = (const float*)d_in[22];
  const float* rW2   = (const float*)d_in[23];
  const float* rb2   = (const float*)d_in[24];
  const float* rW3   = (const float*)d_in[25];
  const float* rb3   = (const float*)d_in[26];
  const int* paths   = (const int*)d_in[27];
  const int* seqs    = (const int*)d_in[28];
  const int* nodes   = (const int*)d_in[29];
  const int* adj_idx = (const int*)d_in[30];
  int E = in_sizes[27];

  /* workspace carve (256B aligned) */
  char* w = (char*)d_ws;
  auto alloc = [&](size_t nbytes)->void*{ void* r=(void*)w; w += (nbytes + 255) & ~(size_t)255; return r; };
  float* ns     = (float*)alloc((size_t)NN*DD*4);
  float* gout   = (float*)alloc((size_t)NN*DD*4);
  float* psA    = (float*)alloc((size_t)NP*DD*4);
  float* psB    = (float*)alloc((size_t)NP*DD*4);
  float* xp     = (float*)alloc((size_t)NN*NHD*4);
  float* es     = (float*)alloc((size_t)NN*NH*4);
  float* en     = (float*)alloc((size_t)NN*NH*4);
  float* adjm   = (float*)alloc((size_t)NN*NN*4);
  float* xgp    = (float*)alloc((size_t)NN*G3*4);
  float* xgb    = (float*)alloc((size_t)NN*G3*4);
  float* m2     = (float*)alloc((size_t)NN*DD*4);
  float* outbuf = (float*)alloc((size_t)E*DD*4);
  int* start    = (int*)alloc((size_t)NP*4);
  int* lens     = (int*)alloc((size_t)NP*4);
  int* counts   = (int*)alloc((size_t)NN*4);
  int* offsets  = (int*)alloc((size_t)NN*4);
  int* cursor   = (int*)alloc((size_t)NN*4);
  int* bucket   = (int*)alloc((size_t)E*4);
  (void)ws_size; (void)n_in; (void)out_size;

  /* one-time (per launch) setup */
  hipMemsetAsync(adjm, 0, (size_t)NN*NN*4, stream);
  hipMemsetAsync(counts, 0, (size_t)NN*4, stream);
  k_init_ns<<<NN,DD,0,stream>>>(ns, qpol, w1, w2, w3, qs);
  k_init_ps<<<(NP*DD+255)/256,256,0,stream>>>(psA, bw, ToS);
  k_adj<<<16,256,0,stream>>>(adjm, adj_idx, lc);
  k_meta<<<(E+255)/256,256,0,stream>>>(paths, seqs, start, lens, E);
  k_count<<<(E+255)/256,256,0,stream>>>(nodes, counts, E);
  k_scan<<<1,NN,0,stream>>>(counts, offsets, cursor);
  k_fill<<<(E+255)/256,256,0,stream>>>(nodes, cursor, bucket, E);

  float* ps_cur = psA; float* ps_nxt = psB;
  for (int t=0;t<3;t++){
    k_xp<<<dim3(NN/16, NHD/64),256,0,stream>>>(ns, gat_W, xp);
    k_gat_e<<<dim3(NN,NH),64,0,stream>>>(xp, gat_as, gat_an, es, en);
    k_gat_bias<<<NN,DD,0,stream>>>(gout, gat_b);
    k_attn<<<dim3(NH, NN/32),256,0,stream>>>(xp, es, en, adjm, gout);
    k_xg<<<dim3(NN,3),128,0,stream>>>(gout, Wp, bp, xgp);
    k_xg<<<dim3(NN,3),128,0,stream>>>(gout, Wb, bb, xgb);
    k_gru<<<NP/32,256,0,stream>>>(ps_cur, ps_nxt, xgp, Up, bp+G3, start, lens, nodes, outbuf, 0);
    k_gru<<<NP/32,256,0,stream>>>(ps_cur, nullptr, xgb, Ub, bb+G3, start, lens, nodes, outbuf, 1);
    k_m2<<<NN,DD,0,stream>>>(outbuf, counts, offsets, bucket, m2);
    k_ngru<<<NN,DD,0,stream>>>(m2, gout, Wn, Un, bn, ns);
    float* tmp = ps_cur; ps_cur = ps_nxt; ps_nxt = tmp;
  }
  k_read<<<NP/16,256,0,stream>>>(ps_cur, rW1, rb1, rW2, rb2, rW3, rb3, (float*)d_out);
}

// Round 2
// 2270.940 us; speedup vs baseline: 3.5019x; 3.5019x over previous
//
#include <hip/hip_runtime.h>
#include <math.h>

#define NN 512
#define NP 20000
#define DD 128
#define NH 24
#define G3 384
#define NHD 3072  /* NH*DD */

typedef __attribute__((ext_vector_type(8))) short bf8_t;   /* 8 bf16 */
typedef __attribute__((ext_vector_type(4))) float f4_t;

__device__ __forceinline__ float sigf(float x){ return 1.f/(1.f+expf(-x)); }
__device__ __forceinline__ unsigned short f2bf(float f){
  unsigned int u = __float_as_uint(f);
  unsigned int r = (u + 0x7fffu + ((u>>16)&1u)) >> 16;
  return (unsigned short)r;
}
__device__ __forceinline__ float bf2f(unsigned short h){
  return __uint_as_float(((unsigned int)h)<<16);
}

/* ---------------- init ---------------- */
__global__ void k_init_ns(float* ns, const float* qp, const float* w1, const float* w2,
                          const float* w3, const float* qs){
  int n = blockIdx.x, c = threadIdx.x;
  float v = 0.f;
  if (c==0) v=qp[n]; else if (c==1) v=w1[n]; else if (c==2) v=w2[n]; else if (c==3) v=w3[n];
  else if (c<7) v=qs[n*3 + (c-4)];
  ns[n*DD+c]=v;
}

__global__ void k_init_ps(float* ps, const float* bw, const float* tos){
  int i = blockIdx.x*256 + threadIdx.x;
  if (i >= NP*DD) return;
  int p = i>>7, c = i&127;
  float v=0.f; if(c==0) v=bw[p]; else if(c==1) v=tos[p];
  ps[i]=v;
}

__global__ void k_adj(float* adjm, const int* idx, const float* lc){
  int l = blockIdx.x*256+threadIdx.x; if(l>=4096) return;
  adjm[idx[l]] = (lc[l]!=0.f)?1.f:0.f;
}

__global__ void k_meta(const int* paths, const int* seqs, int* start, int* lens, int E){
  int e = blockIdx.x*256+threadIdx.x; if(e>=E) return;
  int p=paths[e], s=seqs[e];
  if (s==0) start[p]=e;
  if (e==E-1 || paths[e+1]!=p) lens[p]=s+1;
}

__global__ void k_count(const int* nodes, int* counts, int E){
  int e = blockIdx.x*256+threadIdx.x; if(e>=E) return;
  atomicAdd(&counts[nodes[e]],1);
}

__global__ void k_scan(const int* counts, int* offsets, int* cursor){
  __shared__ int sh[NN];
  int t=threadIdx.x; int v=counts[t]; sh[t]=v; __syncthreads();
  for (int d=1; d<NN; d<<=1){
    int u = (t>=d)? sh[t-d] : 0;
    __syncthreads();
    sh[t]+=u;
    __syncthreads();
  }
  int ex = sh[t]-v;
  offsets[t]=ex; cursor[t]=ex;
}

__global__ void k_fill(const int* nodes, int* cursor, int* bucket, int E){
  int e = blockIdx.x*256+threadIdx.x; if(e>=E) return;
  int pos = atomicAdd(&cursor[nodes[e]],1);
  bucket[pos]=e;
}

/* build transposed split-bf16 U: Ut[col][k], col 0..383, k 0..127 */
__global__ void k_ut(const float* __restrict__ U, unsigned short* __restrict__ Uth,
                     unsigned short* __restrict__ Utl){
  int i = blockIdx.x*256 + threadIdx.x;
  if (i >= G3*DD) return;
  int col = i >> 7, k = i & 127;
  float v = U[(size_t)k*G3 + col];
  unsigned short h = f2bf(v);
  float rf = v - bf2f(h);
  Uth[i] = h; Utl[i] = f2bf(rf);
}

/* ---------------- GAT ---------------- */
__global__ __launch_bounds__(256) void k_xp(const float* __restrict__ ns,
                                            const float* __restrict__ W,
                                            float* __restrict__ xp){
  __shared__ float A[16][130];
  int r0 = blockIdx.x*16, c0 = blockIdx.y*64;
  int tid = threadIdx.x;
  for (int idx=tid; idx<16*128; idx+=256){ int r=idx>>7,k=idx&127; A[r][k]=ns[(r0+r)*DD+k]; }
  __syncthreads();
  int cc = c0 + (tid&63); int rq = tid>>6;
  float a0=0.f,a1=0.f,a2=0.f,a3=0.f;
  for (int k=0;k<128;k++){
    float b = W[(size_t)k*NHD + cc];
    a0 += A[rq*4+0][k]*b; a1 += A[rq*4+1][k]*b; a2 += A[rq*4+2][k]*b; a3 += A[rq*4+3][k]*b;
  }
  xp[(size_t)(r0+rq*4+0)*NHD+cc]=a0;
  xp[(size_t)(r0+rq*4+1)*NHD+cc]=a1;
  xp[(size_t)(r0+rq*4+2)*NHD+cc]=a2;
  xp[(size_t)(r0+rq*4+3)*NHD+cc]=a3;
}

__global__ void k_gat_e(const float* __restrict__ xp, const float* __restrict__ as_,
                        const float* __restrict__ an_, float* es, float* en){
  int n = blockIdx.x, h = blockIdx.y, t = threadIdx.x; /* 64 threads */
  const float* xr = xp + ((size_t)n*NH + h)*DD;
  const float* ar = as_ + h*DD; const float* br = an_ + h*DD;
  float s1 = xr[t]*ar[t] + xr[t+64]*ar[t+64];
  float s2 = xr[t]*br[t] + xr[t+64]*br[t+64];
  for (int o=32;o>0;o>>=1){ s1 += __shfl_down(s1,o); s2 += __shfl_down(s2,o); }
  if (t==0){ es[n*NH+h]=s1; en[n*NH+h]=s2; }
}

__global__ void k_gat_bias(float* gout, const float* gb){
  int n = blockIdx.x, c = threadIdx.x;
  gout[n*DD+c] = gb[c];
}

__global__ __launch_bounds__(256) void k_attn(const float* __restrict__ xp,
                      const float* __restrict__ es, const float* __restrict__ en,
                      const float* __restrict__ adjm, float* __restrict__ gout){
  __shared__ float lg[32][513];
  __shared__ float mxs[32], isms[32];
  int h = blockIdx.x, it = blockIdx.y; int i0 = it*32; int tid = threadIdx.x;
  for (int idx=tid; idx<32*512; idx+=256){
    int ii = idx>>9, j = idx&511;
    float l = es[(i0+ii)*NH+h] + en[j*NH+h];
    l = (l>=0.f)? l : 0.2f*l;
    if (adjm[(size_t)(i0+ii)*NN + j]==0.f) l = -1000000000.0f;
    lg[ii][j] = l;
  }
  __syncthreads();
  {
    int t8 = tid&7, ii = tid>>3;
    float m = -INFINITY;
    for (int j=t8;j<512;j+=8) m = fmaxf(m, lg[ii][j]);
    for (int o=4;o>0;o>>=1) m = fmaxf(m, __shfl_xor(m, o));
    float s=0.f;
    for (int j=t8;j<512;j+=8) s += expf(lg[ii][j]-m);
    for (int o=4;o>0;o>>=1) s += __shfl_xor(s,o);
    if (t8==0){ mxs[ii]=m; isms[ii]=1.f/s; }
  }
  __syncthreads();
  for (int idx=tid; idx<32*512; idx+=256){
    int ii = idx>>9, j = idx&511;
    lg[ii][j] = expf(lg[ii][j]-mxs[ii])*isms[ii];
  }
  __syncthreads();
  int cq = tid&31, iq = tid>>5; int c = cq*4;
  float4 acc0=make_float4(0,0,0,0), acc1=acc0, acc2=acc0, acc3=acc0;
  for (int j=0;j<512;j++){
    const float4 xv = *(const float4*)(xp + ((size_t)j*NH + h)*DD + c);
    float p0 = lg[iq*4+0][j], p1 = lg[iq*4+1][j], p2 = lg[iq*4+2][j], p3 = lg[iq*4+3][j];
    acc0.x+=p0*xv.x; acc0.y+=p0*xv.y; acc0.z+=p0*xv.z; acc0.w+=p0*xv.w;
    acc1.x+=p1*xv.x; acc1.y+=p1*xv.y; acc1.z+=p1*xv.z; acc1.w+=p1*xv.w;
    acc2.x+=p2*xv.x; acc2.y+=p2*xv.y; acc2.z+=p2*xv.z; acc2.w+=p2*xv.w;
    acc3.x+=p3*xv.x; acc3.y+=p3*xv.y; acc3.z+=p3*xv.z; acc3.w+=p3*xv.w;
  }
  const float inv = 1.f/24.f;
  float* o0 = gout + (size_t)(i0+iq*4+0)*DD + c;
  float* o1 = gout + (size_t)(i0+iq*4+1)*DD + c;
  float* o2 = gout + (size_t)(i0+iq*4+2)*DD + c;
  float* o3 = gout + (size_t)(i0+iq*4+3)*DD + c;
  atomicAdd(o0+0,acc0.x*inv); atomicAdd(o0+1,acc0.y*inv); atomicAdd(o0+2,acc0.z*inv); atomicAdd(o0+3,acc0.w*inv);
  atomicAdd(o1+0,acc1.x*inv); atomicAdd(o1+1,acc1.y*inv); atomicAdd(o1+2,acc1.z*inv); atomicAdd(o1+3,acc1.w*inv);
  atomicAdd(o2+0,acc2.x*inv); atomicAdd(o2+1,acc2.y*inv); atomicAdd(o2+2,acc2.z*inv); atomicAdd(o2+3,acc2.w*inv);
  atomicAdd(o3+0,acc3.x*inv); atomicAdd(o3+1,acc3.y*inv); atomicAdd(o3+2,acc3.z*inv); atomicAdd(o3+3,acc3.w*inv);
}

__global__ void k_xg(const float* __restrict__ gout, const float* __restrict__ W,
                     const float* __restrict__ b0, float* __restrict__ out){
  int n = blockIdx.x; int j = blockIdx.y*128 + threadIdx.x;
  const float* g = gout + (size_t)n*DD;
  float acc = b0[j];
  for (int k=0;k<128;k++) acc += g[k]*W[(size_t)k*G3 + j];
  out[(size_t)n*G3+j] = acc;
}

/* ---------------- path GRU via split-bf16 MFMA ----------------
   block = 32 paths, 512 threads = 8 waves; wave w owns output cols
   w*16..w*16+15 of each of the 3 gates.
   A (H) 32x128 fp32 in LDS (stride 132), split to bf16 hi/lo per k-tile.
   B (U^T) pre-split bf16 [384][128].
   mfma_f32_16x16x32_bf16:
     A: lane l -> row l&15,  k = (l>>4)*8 + j
     B: lane l -> col l&15,  k = (l>>4)*8 + j
     C/D: lane l, reg q -> col l&15, row (l>>4)*4 + q   */
__global__ __launch_bounds__(512) void k_gru_mfma(
    const float* __restrict__ ps_in, float* __restrict__ ps_out,
    const float* __restrict__ xg,
    const unsigned short* __restrict__ Uth, const unsigned short* __restrict__ Utl,
    const float* __restrict__ b1,
    const int* __restrict__ start, const int* __restrict__ lens,
    const int* __restrict__ nodes, float* __restrict__ outbuf, int reverse)
{
  __shared__ float Hs[32][132];
  __shared__ int Ls[32], Ss[32];
  int pb = blockIdx.x*32;
  int tid = threadIdx.x;
  int w = tid>>6, l = tid&63;
  int lr = l&15;        /* A-row / B-col / C-col within tile */
  int lg = l>>4;        /* k-group / C row-group */
  for (int idx=tid; idx<32*128; idx+=512){ int pp=idx>>7,kk=idx&127; Hs[pp][kk]=ps_in[(size_t)(pb+pp)*DD+kk]; }
  if (tid<32){ Ls[tid]=lens[pb+tid]; Ss[tid]=start[pb+tid]; }
  __syncthreads();
  int nbase = w*16;
  int c = nbase + lr;   /* output col 0..127 this lane handles */
  for (int s=0;s<8;s++){
    f4_t accz0=(f4_t)(0.f), accz1=(f4_t)(0.f);
    f4_t accr0=(f4_t)(0.f), accr1=(f4_t)(0.f);
    f4_t acch0=(f4_t)(0.f), acch1=(f4_t)(0.f);
    #pragma unroll
    for (int kt=0; kt<4; kt++){
      bf8_t Ahi0, Alo0, Ahi1, Alo1;
      {
        const float* hr0 = &Hs[lr][kt*32 + lg*8];
        const float* hr1 = &Hs[16+lr][kt*32 + lg*8];
        #pragma unroll
        for (int j=0;j<8;j++){
          float v0 = hr0[j], v1 = hr1[j];
          unsigned short h0 = f2bf(v0), h1 = f2bf(v1);
          Ahi0[j]=(short)h0; Alo0[j]=(short)f2bf(v0-bf2f(h0));
          Ahi1[j]=(short)h1; Alo1[j]=(short)f2bf(v1-bf2f(h1));
        }
      }
      size_t kof = (size_t)kt*32 + lg*8;
      const bf8_t Bhz = *(const bf8_t*)(Uth + ((size_t)(      c))*128 + kof);
      const bf8_t Blz = *(const bf8_t*)(Utl + ((size_t)(      c))*128 + kof);
      const bf8_t Bhr = *(const bf8_t*)(Uth + ((size_t)(128 + c))*128 + kof);
      const bf8_t Blr = *(const bf8_t*)(Utl + ((size_t)(128 + c))*128 + kof);
      const bf8_t Bhh = *(const bf8_t*)(Uth + ((size_t)(256 + c))*128 + kof);
      const bf8_t Blh = *(const bf8_t*)(Utl + ((size_t)(256 + c))*128 + kof);
      accz0 = __builtin_amdgcn_mfma_f32_16x16x32_bf16(Ahi0, Bhz, accz0, 0,0,0);
      accz0 = __builtin_amdgcn_mfma_f32_16x16x32_bf16(Alo0, Bhz, accz0, 0,0,0);
      accz0 = __builtin_amdgcn_mfma_f32_16x16x32_bf16(Ahi0, Blz, accz0, 0,0,0);
      accz1 = __builtin_amdgcn_mfma_f32_16x16x32_bf16(Ahi1, Bhz, accz1, 0,0,0);
      accz1 = __builtin_amdgcn_mfma_f32_16x16x32_bf16(Alo1, Bhz, accz1, 0,0,0);
      accz1 = __builtin_amdgcn_mfma_f32_16x16x32_bf16(Ahi1, Blz, accz1, 0,0,0);
      accr0 = __builtin_amdgcn_mfma_f32_16x16x32_bf16(Ahi0, Bhr, accr0, 0,0,0);
      accr0 = __builtin_amdgcn_mfma_f32_16x16x32_bf16(Alo0, Bhr, accr0, 0,0,0);
      accr0 = __builtin_amdgcn_mfma_f32_16x16x32_bf16(Ahi0, Blr, accr0, 0,0,0);
      accr1 = __builtin_amdgcn_mfma_f32_16x16x32_bf16(Ahi1, Bhr, accr1, 0,0,0);
      accr1 = __builtin_amdgcn_mfma_f32_16x16x32_bf16(Alo1, Bhr, accr1, 0,0,0);
      accr1 = __builtin_amdgcn_mfma_f32_16x16x32_bf16(Ahi1, Blr, accr1, 0,0,0);
      acch0 = __builtin_amdgcn_mfma_f32_16x16x32_bf16(Ahi0, Bhh, acch0, 0,0,0);
      acch0 = __builtin_amdgcn_mfma_f32_16x16x32_bf16(Alo0, Bhh, acch0, 0,0,0);
      acch0 = __builtin_amdgcn_mfma_f32_16x16x32_bf16(Ahi0, Blh, acch0, 0,0,0);
      acch1 = __builtin_amdgcn_mfma_f32_16x16x32_bf16(Ahi1, Bhh, acch1, 0,0,0);
      acch1 = __builtin_amdgcn_mfma_f32_16x16x32_bf16(Alo1, Bhh, acch1, 0,0,0);
      acch1 = __builtin_amdgcn_mfma_f32_16x16x32_bf16(Ahi1, Blh, acch1, 0,0,0);
    }
    /* epilogue: lane covers paths p = mt*16 + lg*4 + q, col c */
    float hnew[2][4]; int actv[2][4]; int evec[2][4];
    #pragma unroll
    for (int mt=0; mt<2; mt++){
      #pragma unroll
      for (int q=0; q<4; q++){
        int p = mt*16 + lg*4 + q;
        int L = Ls[p];
        int act = (s < L);
        actv[mt][q] = act;
        int pos = reverse ? (L-1-s) : s;
        int e = Ss[p] + pos;
        evec[mt][q] = e;
        if (act){
          float az = mt ? ((mt==1)?( (q==0)?accz1.x:(q==1)?accz1.y:(q==2)?accz1.z:accz1.w ):0.f)
                        : ( (q==0)?accz0.x:(q==1)?accz0.y:(q==2)?accz0.z:accz0.w );
          float ar = mt ? ( (q==0)?accr1.x:(q==1)?accr1.y:(q==2)?accr1.z:accr1.w )
                        : ( (q==0)?accr0.x:(q==1)?accr0.y:(q==2)?accr0.z:accr0.w );
          float ah = mt ? ( (q==0)?acch1.x:(q==1)?acch1.y:(q==2)?acch1.z:acch1.w )
                        : ( (q==0)?acch0.x:(q==1)?acch0.y:(q==2)?acch0.z:acch0.w );
          int nid = nodes[e];
          const float* xr = xg + (size_t)nid*G3;
          float z = sigf(xr[c]     + az + b1[c]);
          float r = sigf(xr[128+c] + ar + b1[128+c]);
          float hc= tanhf(xr[256+c] + r*(ah + b1[256+c]));
          hnew[mt][q] = z*Hs[p][c] + (1.f-z)*hc;
        }
      }
    }
    __syncthreads();
    #pragma unroll
    for (int mt=0; mt<2; mt++){
      #pragma unroll
      for (int q=0; q<4; q++){
        if (actv[mt][q]){
          int p = mt*16 + lg*4 + q;
          Hs[p][c] = hnew[mt][q];
          float* o = outbuf + (size_t)evec[mt][q]*DD + c;
          if (!reverse) *o = hnew[mt][q];
          else          *o += hnew[mt][q];
        }
      }
    }
    __syncthreads();
  }
  if (ps_out){
    for (int idx=tid; idx<32*128; idx+=512){ int pp=idx>>7,kk=idx&127; ps_out[(size_t)(pb+pp)*DD+kk]=Hs[pp][kk]; }
  }
}

/* ---------------- m2 + node GRU ---------------- */
__global__ void k_m2(const float* __restrict__ outbuf, const int* __restrict__ counts,
                     const int* __restrict__ offsets, const int* __restrict__ bucket,
                     float* __restrict__ m2){
  int n = blockIdx.x; int c = threadIdx.x; /* 128 threads */
  int cnt = counts[n], off = offsets[n];
  float acc = 0.f;
  for (int idx=0; idx<cnt; ++idx){
    int e = bucket[off+idx];
    acc += outbuf[(size_t)e*DD + c];
  }
  m2[n*DD+c] = acc;
}

__global__ void k_ngru(const float* __restrict__ m2, const float* __restrict__ gout,
                       const float* __restrict__ Wn, const float* __restrict__ Un,
                       const float* __restrict__ bn, float* __restrict__ ns){
  int n = blockIdx.x, c = threadIdx.x; /* 128 threads */
  float xz=0.f,xr=0.f,xh=0.f,hz=0.f,hr=0.f,hh=0.f;
  const float* x = m2 + (size_t)n*DD; const float* h = gout + (size_t)n*DD;
  for (int k=0;k<128;k++){
    float xk=x[k], hk=h[k];
    const float* wr = Wn + (size_t)k*G3; const float* ur = Un + (size_t)k*G3;
    xz += xk*wr[c]; xr += xk*wr[128+c]; xh += xk*wr[256+c];
    hz += hk*ur[c]; hr += hk*ur[128+c]; hh += hk*ur[256+c];
  }
  float z = sigf(xz+bn[c]     + hz+bn[G3+c]);
  float r = sigf(xr+bn[128+c] + hr+bn[G3+128+c]);
  float hc = tanhf(xh+bn[256+c] + r*(hh+bn[G3+256+c]));
  ns[n*DD+c] = z*h[c] + (1.f-z)*hc;
}

/* ---------------- readout ---------------- */
#define RFMA(q) { float4 w_ = *(const float4*)(wr+(q)*4); \
  acc[(q)*4+0]+=pk*w_.x; acc[(q)*4+1]+=pk*w_.y; acc[(q)*4+2]+=pk*w_.z; acc[(q)*4+3]+=pk*w_.w; }

__global__ __launch_bounds__(256) void k_read(const float* __restrict__ ps,
    const float* __restrict__ rW1, const float* __restrict__ rb1,
    const float* __restrict__ rW2, const float* __restrict__ rb2,
    const float* __restrict__ rW3, const float* __restrict__ rb3, float* __restrict__ out)
{
  __shared__ float psl[16][129];
  __shared__ float h1l[16][257];
  __shared__ float h2l[16][257];
  __shared__ float red[16][17];
  int pb = blockIdx.x*16; int tid = threadIdx.x;
  int p = tid&15, cg = tid>>4; /* cg 0..15 */
  for (int idx=tid; idx<16*128; idx+=256){ int pp=idx>>7,k=idx&127; psl[pp][k]=ps[(size_t)(pb+pp)*DD+k]; }
  __syncthreads();
  {
    float acc[16];
    #pragma unroll
    for (int i=0;i<16;i++) acc[i]=rb1[cg*16+i];
    for (int k=0;k<128;k++){
      float pk = psl[p][k];
      const float* wr = rW1 + (size_t)k*256 + cg*16;
      RFMA(0) RFMA(1) RFMA(2) RFMA(3)
    }
    #pragma unroll
    for (int i=0;i<16;i++){
      float x = acc[i];
      h1l[p][cg*16+i] = 1.0507009873554805f * (x>0.f ? x : 1.6732632423543772f*expm1f(x));
    }
  }
  __syncthreads();
  {
    float acc[16];
    #pragma unroll
    for (int i=0;i<16;i++) acc[i]=rb2[cg*16+i];
    for (int k=0;k<256;k++){
      float pk = h1l[p][k];
      const float* wr = rW2 + (size_t)k*256 + cg*16;
      RFMA(0) RFMA(1) RFMA(2) RFMA(3)
    }
    #pragma unroll
    for (int i=0;i<16;i++) h2l[p][cg*16+i] = fmaxf(acc[i],0.f);
  }
  __syncthreads();
  float s=0.f;
  #pragma unroll
  for (int i=0;i<16;i++) s += h2l[p][cg*16+i]*rW3[cg*16+i];
  red[p][cg]=s; __syncthreads();
  if (tid<16){
    float t=rb3[0];
    for (int q=0;q<16;q++) t += red[tid][q];
    out[pb+tid]=t;
  }
}

/* ---------------- host ---------------- */
extern "C" void kernel_launch(void* const* d_in, const int* in_sizes, int n_in,
                              void* d_out, int out_size, void* d_ws, size_t ws_size,
                              hipStream_t stream)
{
  const float* ToS   = (const float*)d_in[0];
  const float* bw    = (const float*)d_in[1];
  const float* qpol  = (const float*)d_in[2];
  const float* w1    = (const float*)d_in[3];
  const float* w2    = (const float*)d_in[4];
  const float* w3    = (const float*)d_in[5];
  const float* qs    = (const float*)d_in[6];
  const float* lc    = (const float*)d_in[7];
  const float* gat_W = (const float*)d_in[8];
  const float* gat_as= (const float*)d_in[9];
  const float* gat_an= (const float*)d_in[10];
  const float* gat_b = (const float*)d_in[11];
  const float* Wp    = (const float*)d_in[12];
  const float* Up    = (const float*)d_in[13];
  const float* bp    = (const float*)d_in[14];
  const float* Wb    = (const float*)d_in[15];
  const float* Ub    = (const float*)d_in[16];
  const float* bb    = (const float*)d_in[17];
  const float* Wn    = (const float*)d_in[18];
  const float* Un    = (const float*)d_in[19];
  const float* bn    = (const float*)d_in[20];
  const float* rW1   = (const float*)d_in[21];
  const float* rb1   = (const float*)d_in[22];
  const float* rW2   = (const float*)d_in[23];
  const float* rb2   = (const float*)d_in[24];
  const float* rW3   = (const float*)d_in[25];
  const float* rb3   = (const float*)d_in[26];
  const int* paths   = (const int*)d_in[27];
  const int* seqs    = (const int*)d_in[28];
  const int* nodes   = (const int*)d_in[29];
  const int* adj_idx = (const int*)d_in[30];
  int E = in_sizes[27];

  char* w = (char*)d_ws;
  auto alloc = [&](size_t nbytes)->void*{ void* r=(void*)w; w += (nbytes + 255) & ~(size_t)255; return r; };
  float* ns     = (float*)alloc((size_t)NN*DD*4);
  float* gout   = (float*)alloc((size_t)NN*DD*4);
  float* psA    = (float*)alloc((size_t)NP*DD*4);
  float* psB    = (float*)alloc((size_t)NP*DD*4);
  float* xp     = (float*)alloc((size_t)NN*NHD*4);
  float* es     = (float*)alloc((size_t)NN*NH*4);
  float* en     = (float*)alloc((size_t)NN*NH*4);
  float* adjm   = (float*)alloc((size_t)NN*NN*4);
  float* xgp    = (float*)alloc((size_t)NN*G3*4);
  float* xgb    = (float*)alloc((size_t)NN*G3*4);
  float* m2     = (float*)alloc((size_t)NN*DD*4);
  float* outbuf = (float*)alloc((size_t)E*DD*4);
  unsigned short* Uthp = (unsigned short*)alloc((size_t)G3*DD*2);
  unsigned short* Utlp = (unsigned short*)alloc((size_t)G3*DD*2);
  unsigned short* Uthb = (unsigned short*)alloc((size_t)G3*DD*2);
  unsigned short* Utlb = (unsigned short*)alloc((size_t)G3*DD*2);
  int* start    = (int*)alloc((size_t)NP*4);
  int* lens     = (int*)alloc((size_t)NP*4);
  int* counts   = (int*)alloc((size_t)NN*4);
  int* offsets  = (int*)alloc((size_t)NN*4);
  int* cursor   = (int*)alloc((size_t)NN*4);
  int* bucket   = (int*)alloc((size_t)E*4);
  (void)ws_size; (void)n_in; (void)out_size;

  hipMemsetAsync(adjm, 0, (size_t)NN*NN*4, stream);
  hipMemsetAsync(counts, 0, (size_t)NN*4, stream);
  k_init_ns<<<NN,DD,0,stream>>>(ns, qpol, w1, w2, w3, qs);
  k_init_ps<<<(NP*DD+255)/256,256,0,stream>>>(psA, bw, ToS);
  k_adj<<<16,256,0,stream>>>(adjm, adj_idx, lc);
  k_meta<<<(E+255)/256,256,0,stream>>>(paths, seqs, start, lens, E);
  k_count<<<(E+255)/256,256,0,stream>>>(nodes, counts, E);
  k_scan<<<1,NN,0,stream>>>(counts, offsets, cursor);
  k_fill<<<(E+255)/256,256,0,stream>>>(nodes, cursor, bucket, E);
  k_ut<<<(G3*DD+255)/256,256,0,stream>>>(Up, Uthp, Utlp);
  k_ut<<<(G3*DD+255)/256,256,0,stream>>>(Ub, Uthb, Utlb);

  float* ps_cur = psA; float* ps_nxt = psB;
  for (int t=0;t<3;t++){
    k_xp<<<dim3(NN/16, NHD/64),256,0,stream>>>(ns, gat_W, xp);
    k_gat_e<<<dim3(NN,NH),64,0,stream>>>(xp, gat_as, gat_an, es, en);
    k_gat_bias<<<NN,DD,0,stream>>>(gout, gat_b);
    k_attn<<<dim3(NH, NN/32),256,0,stream>>>(xp, es, en, adjm, gout);
    k_xg<<<dim3(NN,3),128,0,stream>>>(gout, Wp, bp, xgp);
    k_xg<<<dim3(NN,3),128,0,stream>>>(gout, Wb, bb, xgb);
    k_gru_mfma<<<NP/32,512,0,stream>>>(ps_cur, ps_nxt, xgp, Uthp, Utlp, bp+G3, start, lens, nodes, outbuf, 0);
    k_gru_mfma<<<NP/32,512,0,stream>>>(ps_cur, nullptr, xgb, Uthb, Utlb, bb+G3, start, lens, nodes, outbuf, 1);
    k_m2<<<NN,DD,0,stream>>>(outbuf, counts, offsets, bucket, m2);
    k_ngru<<<NN,DD,0,stream>>>(m2, gout, Wn, Un, bn, ns);
    float* tmp = ps_cur; ps_cur = ps_nxt; ps_nxt = tmp;
  }
  k_read<<<NP/16,256,0,stream>>>(ps_cur, rW1, rb1, rW2, rb2, rW3, rb3, (float*)d_out);
}

// Round 3
// 1767.508 us; speedup vs baseline: 4.4994x; 1.2848x over previous
//
#include <hip/hip_runtime.h>
#include <math.h>

#define NN 512
#define NP 20000
#define DD 128
#define NH 24
#define G3 384
#define NHD 3072  /* NH*DD */

typedef __attribute__((ext_vector_type(8))) short bf8_t;   /* 8 bf16 */
typedef __attribute__((ext_vector_type(4))) float f4_t;
typedef unsigned short ushort_t;

__device__ __forceinline__ float sigf(float x){ return 1.f/(1.f+expf(-x)); }
__device__ __forceinline__ unsigned short f2bf(float f){
  unsigned int u = __float_as_uint(f);
  unsigned int r = (u + 0x7fffu + ((u>>16)&1u)) >> 16;
  return (unsigned short)r;
}
__device__ __forceinline__ float bf2f(unsigned short h){
  return __uint_as_float(((unsigned int)h)<<16);
}

/* ---------------- init ---------------- */
__global__ void k_init_ns(float* ns, const float* qp, const float* w1, const float* w2,
                          const float* w3, const float* qs){
  int n = blockIdx.x, c = threadIdx.x;
  float v = 0.f;
  if (c==0) v=qp[n]; else if (c==1) v=w1[n]; else if (c==2) v=w2[n]; else if (c==3) v=w3[n];
  else if (c<7) v=qs[n*3 + (c-4)];
  ns[n*DD+c]=v;
}

__global__ void k_init_ps(float* ps, const float* bw, const float* tos){
  int i = blockIdx.x*256 + threadIdx.x;
  if (i >= NP*DD) return;
  int p = i>>7, c = i&127;
  float v=0.f; if(c==0) v=bw[p]; else if(c==1) v=tos[p];
  ps[i]=v;
}

__global__ void k_adj(float* adjm, const int* idx, const float* lc){
  int l = blockIdx.x*256+threadIdx.x; if(l>=4096) return;
  adjm[idx[l]] = (lc[l]!=0.f)?1.f:0.f;
}

__global__ void k_meta(const int* paths, const int* seqs, int* start, int* lens, int E){
  int e = blockIdx.x*256+threadIdx.x; if(e>=E) return;
  int p=paths[e], s=seqs[e];
  if (s==0) start[p]=e;
  if (e==E-1 || paths[e+1]!=p) lens[p]=s+1;
}

__global__ void k_count(const int* nodes, int* counts, int E){
  int e = blockIdx.x*256+threadIdx.x; if(e>=E) return;
  atomicAdd(&counts[nodes[e]],1);
}

__global__ void k_scan(const int* counts, int* offsets, int* cursor){
  __shared__ int sh[NN];
  int t=threadIdx.x; int v=counts[t]; sh[t]=v; __syncthreads();
  for (int d=1; d<NN; d<<=1){
    int u = (t>=d)? sh[t-d] : 0;
    __syncthreads();
    sh[t]+=u;
    __syncthreads();
  }
  int ex = sh[t]-v;
  offsets[t]=ex; cursor[t]=ex;
}

__global__ void k_fill(const int* nodes, int* cursor, int* bucket, int E){
  int e = blockIdx.x*256+threadIdx.x; if(e>=E) return;
  int pos = atomicAdd(&cursor[nodes[e]],1);
  bucket[pos]=e;
}

/* build transposed split-bf16 U: Ut[col][k], col 0..383, k 0..127 */
__global__ void k_ut(const float* __restrict__ U, unsigned short* __restrict__ Uth,
                     unsigned short* __restrict__ Utl){
  int i = blockIdx.x*256 + threadIdx.x;
  if (i >= G3*DD) return;
  int col = i >> 7, k = i & 127;
  float v = U[(size_t)k*G3 + col];
  unsigned short h = f2bf(v);
  float rf = v - bf2f(h);
  Uth[i] = h; Utl[i] = f2bf(rf);
}

/* ---------------- GAT ---------------- */
__global__ __launch_bounds__(256) void k_xp(const float* __restrict__ ns,
                                            const float* __restrict__ W,
                                            float* __restrict__ xp){
  __shared__ float A[16][130];
  int r0 = blockIdx.x*16, c0 = blockIdx.y*64;
  int tid = threadIdx.x;
  for (int idx=tid; idx<16*128; idx+=256){ int r=idx>>7,k=idx&127; A[r][k]=ns[(r0+r)*DD+k]; }
  __syncthreads();
  int cc = c0 + (tid&63); int rq = tid>>6;
  float a0=0.f,a1=0.f,a2=0.f,a3=0.f;
  for (int k=0;k<128;k++){
    float b = W[(size_t)k*NHD + cc];
    a0 += A[rq*4+0][k]*b; a1 += A[rq*4+1][k]*b; a2 += A[rq*4+2][k]*b; a3 += A[rq*4+3][k]*b;
  }
  xp[(size_t)(r0+rq*4+0)*NHD+cc]=a0;
  xp[(size_t)(r0+rq*4+1)*NHD+cc]=a1;
  xp[(size_t)(r0+rq*4+2)*NHD+cc]=a2;
  xp[(size_t)(r0+rq*4+3)*NHD+cc]=a3;
}

__global__ void k_gat_e(const float* __restrict__ xp, const float* __restrict__ as_,
                        const float* __restrict__ an_, float* es, float* en){
  int n = blockIdx.x, h = blockIdx.y, t = threadIdx.x; /* 64 threads */
  const float* xr = xp + ((size_t)n*NH + h)*DD;
  const float* ar = as_ + h*DD; const float* br = an_ + h*DD;
  float s1 = xr[t]*ar[t] + xr[t+64]*ar[t+64];
  float s2 = xr[t]*br[t] + xr[t+64]*br[t+64];
  for (int o=32;o>0;o>>=1){ s1 += __shfl_down(s1,o); s2 += __shfl_down(s2,o); }
  if (t==0){ es[n*NH+h]=s1; en[n*NH+h]=s2; }
}

__global__ void k_gat_bias(float* gout, const float* gb){
  int n = blockIdx.x, c = threadIdx.x;
  gout[n*DD+c] = gb[c];
}

__global__ __launch_bounds__(256) void k_attn(const float* __restrict__ xp,
                      const float* __restrict__ es, const float* __restrict__ en,
                      const float* __restrict__ adjm, float* __restrict__ gout){
  __shared__ float lg[32][513];
  __shared__ float mxs[32], isms[32];
  int h = blockIdx.x, it = blockIdx.y; int i0 = it*32; int tid = threadIdx.x;
  for (int idx=tid; idx<32*512; idx+=256){
    int ii = idx>>9, j = idx&511;
    float l = es[(i0+ii)*NH+h] + en[j*NH+h];
    l = (l>=0.f)? l : 0.2f*l;
    if (adjm[(size_t)(i0+ii)*NN + j]==0.f) l = -1000000000.0f;
    lg[ii][j] = l;
  }
  __syncthreads();
  {
    int t8 = tid&7, ii = tid>>3;
    float m = -INFINITY;
    for (int j=t8;j<512;j+=8) m = fmaxf(m, lg[ii][j]);
    for (int o=4;o>0;o>>=1) m = fmaxf(m, __shfl_xor(m, o));
    float s=0.f;
    for (int j=t8;j<512;j+=8) s += expf(lg[ii][j]-m);
    for (int o=4;o>0;o>>=1) s += __shfl_xor(s,o);
    if (t8==0){ mxs[ii]=m; isms[ii]=1.f/s; }
  }
  __syncthreads();
  for (int idx=tid; idx<32*512; idx+=256){
    int ii = idx>>9, j = idx&511;
    lg[ii][j] = expf(lg[ii][j]-mxs[ii])*isms[ii];
  }
  __syncthreads();
  int cq = tid&31, iq = tid>>5; int c = cq*4;
  float4 acc0=make_float4(0,0,0,0), acc1=acc0, acc2=acc0, acc3=acc0;
  for (int j=0;j<512;j++){
    const float4 xv = *(const float4*)(xp + ((size_t)j*NH + h)*DD + c);
    float p0 = lg[iq*4+0][j], p1 = lg[iq*4+1][j], p2 = lg[iq*4+2][j], p3 = lg[iq*4+3][j];
    acc0.x+=p0*xv.x; acc0.y+=p0*xv.y; acc0.z+=p0*xv.z; acc0.w+=p0*xv.w;
    acc1.x+=p1*xv.x; acc1.y+=p1*xv.y; acc1.z+=p1*xv.z; acc1.w+=p1*xv.w;
    acc2.x+=p2*xv.x; acc2.y+=p2*xv.y; acc2.z+=p2*xv.z; acc2.w+=p2*xv.w;
    acc3.x+=p3*xv.x; acc3.y+=p3*xv.y; acc3.z+=p3*xv.z; acc3.w+=p3*xv.w;
  }
  const float inv = 1.f/24.f;
  float* o0 = gout + (size_t)(i0+iq*4+0)*DD + c;
  float* o1 = gout + (size_t)(i0+iq*4+1)*DD + c;
  float* o2 = gout + (size_t)(i0+iq*4+2)*DD + c;
  float* o3 = gout + (size_t)(i0+iq*4+3)*DD + c;
  atomicAdd(o0+0,acc0.x*inv); atomicAdd(o0+1,acc0.y*inv); atomicAdd(o0+2,acc0.z*inv); atomicAdd(o0+3,acc0.w*inv);
  atomicAdd(o1+0,acc1.x*inv); atomicAdd(o1+1,acc1.y*inv); atomicAdd(o1+2,acc1.z*inv); atomicAdd(o1+3,acc1.w*inv);
  atomicAdd(o2+0,acc2.x*inv); atomicAdd(o2+1,acc2.y*inv); atomicAdd(o2+2,acc2.z*inv); atomicAdd(o2+3,acc2.w*inv);
  atomicAdd(o3+0,acc3.x*inv); atomicAdd(o3+1,acc3.y*inv); atomicAdd(o3+2,acc3.z*inv); atomicAdd(o3+3,acc3.w*inv);
}

__global__ void k_xg(const float* __restrict__ gout, const float* __restrict__ W,
                     const float* __restrict__ b0, float* __restrict__ out){
  int n = blockIdx.x; int j = blockIdx.y*128 + threadIdx.x;
  const float* g = gout + (size_t)n*DD;
  float acc = b0[j];
  for (int k=0;k<128;k++) acc += g[k]*W[(size_t)k*G3 + j];
  out[(size_t)n*G3+j] = acc;
}

/* ---------------- fused bidirectional path GRU (split-bf16 MFMA) ----------------
   mode==2: fused, grid=2*(NP/32), dir = blockIdx.x&1
   mode==0/1: serial fallback, grid=NP/32, dir=mode; mode==1 accumulates into outF.
   State H kept in LDS as bf16 hi/lo, double-buffered (1 barrier/step).
   mfma_f32_16x16x32_bf16: A row=l&15,k=(l>>4)*8+j; B col=l&15 same k;
   C/D lane l reg q -> col l&15, row (l>>4)*4+q. */
__global__ __launch_bounds__(512) void k_gru2(
    const float* __restrict__ ps_in, float* __restrict__ ps_out,
    const float* __restrict__ xgF, const float* __restrict__ xgB,
    const ushort_t* __restrict__ UthF, const ushort_t* __restrict__ UtlF,
    const ushort_t* __restrict__ UthB, const ushort_t* __restrict__ UtlB,
    const float* __restrict__ b1F, const float* __restrict__ b1B,
    const int* __restrict__ start, const int* __restrict__ lens,
    const int* __restrict__ nodes,
    float* __restrict__ outF, float* __restrict__ outB, int mode)
{
  __shared__ __align__(16) ushort_t HsH[2][32][136];
  __shared__ __align__(16) ushort_t HsL[2][32][136];
  __shared__ int Ls[32], Ss[32];
  __shared__ int nid_l[32][8];

  int dir, pblk;
  if (mode==2){ dir = blockIdx.x & 1; pblk = blockIdx.x >> 1; }
  else        { dir = mode;           pblk = blockIdx.x; }
  const bool rev = (dir==1);
  const float* xg = rev ? xgB : xgF;
  const ushort_t* Uth = rev ? UthB : UthF;
  const ushort_t* Utl = rev ? UtlB : UtlF;
  const float* b1 = rev ? b1B : b1F;
  float* ob = (mode==2) ? (rev ? outB : outF) : outF;
  const bool accum = (mode==1);
  float* psn = rev ? (float*)0 : ps_out;

  int pb = pblk*32;
  int tid = threadIdx.x;
  int w = tid>>6, l = tid&63;
  int lr = l&15, lg = l>>4;
  int c = w*16 + lr;

  for (int idx=tid; idx<32*128; idx+=512){
    int pp=idx>>7, kk=idx&127;
    float v = ps_in[(size_t)(pb+pp)*DD+kk];
    ushort_t hi = f2bf(v);
    HsH[0][pp][kk]=hi; HsL[0][pp][kk]=f2bf(v - bf2f(hi));
  }
  if (tid<32){ Ls[tid]=lens[pb+tid]; Ss[tid]=start[pb+tid]; }
  __syncthreads();
  if (tid<256){
    int p=tid>>3, s=tid&7; int L=Ls[p];
    int nid = 0;
    if (s<L){ int pos = rev ? (L-1-s) : s; nid = nodes[Ss[p]+pos]; }
    nid_l[p][s]=nid;
  }
  __syncthreads();

  /* per-lane path set: i -> p = (i>>2)*16 + lg*4 + (i&3) */
  int Lv[8], Sv[8];
  #pragma unroll
  for (int i=0;i<8;i++){ int p=(i>>2)*16 + lg*4 + (i&3); Lv[i]=Ls[p]; Sv[i]=Ss[p]; }
  float b1z = b1[c], b1r = b1[128+c], b1h = b1[256+c];

  int cur = 0;
  for (int s=0;s<8;s++){
    int nxt = cur^1;
    /* early-issue xg gathers for this step */
    bool act[8]; int e_[8]; float xzv[8], xrv[8], xhv[8];
    #pragma unroll
    for (int i=0;i<8;i++){
      int p=(i>>2)*16 + lg*4 + (i&3);
      act[i] = (s < Lv[i]);
      int pos = rev ? (Lv[i]-1-s) : s;
      e_[i] = Sv[i] + pos;
      int nid = nid_l[p][s];           /* 0 when inactive (pre-filled) */
      const float* xr = xg + (size_t)nid*G3;
      xzv[i]=xr[c]; xrv[i]=xr[128+c]; xhv[i]=xr[256+c];
    }
    /* MFMA block */
    f4_t accz0=(f4_t)(0.f), accz1=(f4_t)(0.f);
    f4_t accr0=(f4_t)(0.f), accr1=(f4_t)(0.f);
    f4_t acch0=(f4_t)(0.f), acch1=(f4_t)(0.f);
    #pragma unroll
    for (int kt=0; kt<4; kt++){
      int kof = kt*32 + lg*8;
      const bf8_t Ahi0 = *(const bf8_t*)&HsH[cur][lr][kof];
      const bf8_t Alo0 = *(const bf8_t*)&HsL[cur][lr][kof];
      const bf8_t Ahi1 = *(const bf8_t*)&HsH[cur][16+lr][kof];
      const bf8_t Alo1 = *(const bf8_t*)&HsL[cur][16+lr][kof];
      const bf8_t Bhz = *(const bf8_t*)(Uth + ((size_t)(      c))*128 + kof);
      const bf8_t Blz = *(const bf8_t*)(Utl + ((size_t)(      c))*128 + kof);
      const bf8_t Bhr = *(const bf8_t*)(Uth + ((size_t)(128 + c))*128 + kof);
      const bf8_t Blr = *(const bf8_t*)(Utl + ((size_t)(128 + c))*128 + kof);
      const bf8_t Bhh = *(const bf8_t*)(Uth + ((size_t)(256 + c))*128 + kof);
      const bf8_t Blh = *(const bf8_t*)(Utl + ((size_t)(256 + c))*128 + kof);
      accz0 = __builtin_amdgcn_mfma_f32_16x16x32_bf16(Ahi0, Bhz, accz0, 0,0,0);
      accz0 = __builtin_amdgcn_mfma_f32_16x16x32_bf16(Alo0, Bhz, accz0, 0,0,0);
      accz0 = __builtin_amdgcn_mfma_f32_16x16x32_bf16(Ahi0, Blz, accz0, 0,0,0);
      accz1 = __builtin_amdgcn_mfma_f32_16x16x32_bf16(Ahi1, Bhz, accz1, 0,0,0);
      accz1 = __builtin_amdgcn_mfma_f32_16x16x32_bf16(Alo1, Bhz, accz1, 0,0,0);
      accz1 = __builtin_amdgcn_mfma_f32_16x16x32_bf16(Ahi1, Blz, accz1, 0,0,0);
      accr0 = __builtin_amdgcn_mfma_f32_16x16x32_bf16(Ahi0, Bhr, accr0, 0,0,0);
      accr0 = __builtin_amdgcn_mfma_f32_16x16x32_bf16(Alo0, Bhr, accr0, 0,0,0);
      accr0 = __builtin_amdgcn_mfma_f32_16x16x32_bf16(Ahi0, Blr, accr0, 0,0,0);
      accr1 = __builtin_amdgcn_mfma_f32_16x16x32_bf16(Ahi1, Bhr, accr1, 0,0,0);
      accr1 = __builtin_amdgcn_mfma_f32_16x16x32_bf16(Alo1, Bhr, accr1, 0,0,0);
      accr1 = __builtin_amdgcn_mfma_f32_16x16x32_bf16(Ahi1, Blr, accr1, 0,0,0);
      acch0 = __builtin_amdgcn_mfma_f32_16x16x32_bf16(Ahi0, Bhh, acch0, 0,0,0);
      acch0 = __builtin_amdgcn_mfma_f32_16x16x32_bf16(Alo0, Bhh, acch0, 0,0,0);
      acch0 = __builtin_amdgcn_mfma_f32_16x16x32_bf16(Ahi0, Blh, acch0, 0,0,0);
      acch1 = __builtin_amdgcn_mfma_f32_16x16x32_bf16(Ahi1, Bhh, acch1, 0,0,0);
      acch1 = __builtin_amdgcn_mfma_f32_16x16x32_bf16(Alo1, Bhh, acch1, 0,0,0);
      acch1 = __builtin_amdgcn_mfma_f32_16x16x32_bf16(Ahi1, Blh, acch1, 0,0,0);
    }
    /* epilogue (each (p,c) has exactly one owner lane) */
#define EPI(i, mt, qq, AZ, AR, AH) { \
    int p = (mt)*16 + lg*4 + (qq); \
    if (act[i]) { \
      float hold = bf2f(HsH[cur][p][c]) + bf2f(HsL[cur][p][c]); \
      float z = sigf(xzv[i] + (AZ) + b1z); \
      float r = sigf(xrv[i] + (AR) + b1r); \
      float hc = tanhf(xhv[i] + r*((AH) + b1h)); \
      float hn = z*hold + (1.f-z)*hc; \
      ushort_t hi2 = f2bf(hn); \
      HsH[nxt][p][c]=hi2; HsL[nxt][p][c]=f2bf(hn - bf2f(hi2)); \
      float* o = ob + (size_t)e_[i]*DD + c; \
      if (accum) *o += hn; else *o = hn; \
    } else { \
      HsH[nxt][p][c]=HsH[cur][p][c]; HsL[nxt][p][c]=HsL[cur][p][c]; \
    } }
    EPI(0,0,0, accz0.x, accr0.x, acch0.x)
    EPI(1,0,1, accz0.y, accr0.y, acch0.y)
    EPI(2,0,2, accz0.z, accr0.z, acch0.z)
    EPI(3,0,3, accz0.w, accr0.w, acch0.w)
    EPI(4,1,0, accz1.x, accr1.x, acch1.x)
    EPI(5,1,1, accz1.y, accr1.y, acch1.y)
    EPI(6,1,2, accz1.z, accr1.z, acch1.z)
    EPI(7,1,3, accz1.w, accr1.w, acch1.w)
#undef EPI
    __syncthreads();
    cur = nxt;
  }
  if (psn){
    for (int idx=tid; idx<32*128; idx+=512){
      int pp=idx>>7, kk=idx&127;
      psn[(size_t)(pb+pp)*DD+kk] = bf2f(HsH[cur][pp][kk]) + bf2f(HsL[cur][pp][kk]);
    }
  }
}

/* ---------------- m2 + node GRU ---------------- */
__global__ void k_m2(const float* __restrict__ outF, const float* __restrict__ outB,
                     const int* __restrict__ counts,
                     const int* __restrict__ offsets, const int* __restrict__ bucket,
                     float* __restrict__ m2){
  int n = blockIdx.x; int c = threadIdx.x; /* 128 threads */
  int cnt = counts[n], off = offsets[n];
  float acc = 0.f;
  if (outB){
    for (int idx=0; idx<cnt; ++idx){
      int e = bucket[off+idx];
      acc += outF[(size_t)e*DD + c] + outB[(size_t)e*DD + c];
    }
  } else {
    for (int idx=0; idx<cnt; ++idx){
      int e = bucket[off+idx];
      acc += outF[(size_t)e*DD + c];
    }
  }
  m2[n*DD+c] = acc;
}

__global__ void k_ngru(const float* __restrict__ m2, const float* __restrict__ gout,
                       const float* __restrict__ Wn, const float* __restrict__ Un,
                       const float* __restrict__ bn, float* __restrict__ ns){
  int n = blockIdx.x, c = threadIdx.x; /* 128 threads */
  float xz=0.f,xr=0.f,xh=0.f,hz=0.f,hr=0.f,hh=0.f;
  const float* x = m2 + (size_t)n*DD; const float* h = gout + (size_t)n*DD;
  for (int k=0;k<128;k++){
    float xk=x[k], hk=h[k];
    const float* wr = Wn + (size_t)k*G3; const float* ur = Un + (size_t)k*G3;
    xz += xk*wr[c]; xr += xk*wr[128+c]; xh += xk*wr[256+c];
    hz += hk*ur[c]; hr += hk*ur[128+c]; hh += hk*ur[256+c];
  }
  float z = sigf(xz+bn[c]     + hz+bn[G3+c]);
  float r = sigf(xr+bn[128+c] + hr+bn[G3+128+c]);
  float hc = tanhf(xh+bn[256+c] + r*(hh+bn[G3+256+c]));
  ns[n*DD+c] = z*h[c] + (1.f-z)*hc;
}

/* ---------------- readout ---------------- */
#define RFMA(q) { float4 w_ = *(const float4*)(wr+(q)*4); \
  acc[(q)*4+0]+=pk*w_.x; acc[(q)*4+1]+=pk*w_.y; acc[(q)*4+2]+=pk*w_.z; acc[(q)*4+3]+=pk*w_.w; }

__global__ __launch_bounds__(256) void k_read(const float* __restrict__ ps,
    const float* __restrict__ rW1, const float* __restrict__ rb1,
    const float* __restrict__ rW2, const float* __restrict__ rb2,
    const float* __restrict__ rW3, const float* __restrict__ rb3, float* __restrict__ out)
{
  __shared__ float psl[16][129];
  __shared__ float h1l[16][257];
  __shared__ float h2l[16][257];
  __shared__ float red[16][17];
  int pb = blockIdx.x*16; int tid = threadIdx.x;
  int p = tid&15, cg = tid>>4; /* cg 0..15 */
  for (int idx=tid; idx<16*128; idx+=256){ int pp=idx>>7,k=idx&127; psl[pp][k]=ps[(size_t)(pb+pp)*DD+k]; }
  __syncthreads();
  {
    float acc[16];
    #pragma unroll
    for (int i=0;i<16;i++) acc[i]=rb1[cg*16+i];
    for (int k=0;k<128;k++){
      float pk = psl[p][k];
      const float* wr = rW1 + (size_t)k*256 + cg*16;
      RFMA(0) RFMA(1) RFMA(2) RFMA(3)
    }
    #pragma unroll
    for (int i=0;i<16;i++){
      float x = acc[i];
      h1l[p][cg*16+i] = 1.0507009873554805f * (x>0.f ? x : 1.6732632423543772f*expm1f(x));
    }
  }
  __syncthreads();
  {
    float acc[16];
    #pragma unroll
    for (int i=0;i<16;i++) acc[i]=rb2[cg*16+i];
    for (int k=0;k<256;k++){
      float pk = h1l[p][k];
      const float* wr = rW2 + (size_t)k*256 + cg*16;
      RFMA(0) RFMA(1) RFMA(2) RFMA(3)
    }
    #pragma unroll
    for (int i=0;i<16;i++) h2l[p][cg*16+i] = fmaxf(acc[i],0.f);
  }
  __syncthreads();
  float s=0.f;
  #pragma unroll
  for (int i=0;i<16;i++) s += h2l[p][cg*16+i]*rW3[cg*16+i];
  red[p][cg]=s; __syncthreads();
  if (tid<16){
    float t=rb3[0];
    for (int q=0;q<16;q++) t += red[tid][q];
    out[pb+tid]=t;
  }
}

/* ---------------- host ---------------- */
extern "C" void kernel_launch(void* const* d_in, const int* in_sizes, int n_in,
                              void* d_out, int out_size, void* d_ws, size_t ws_size,
                              hipStream_t stream)
{
  const float* ToS   = (const float*)d_in[0];
  const float* bw    = (const float*)d_in[1];
  const float* qpol  = (const float*)d_in[2];
  const float* w1    = (const float*)d_in[3];
  const float* w2    = (const float*)d_in[4];
  const float* w3    = (const float*)d_in[5];
  const float* qs    = (const float*)d_in[6];
  const float* lc    = (const float*)d_in[7];
  const float* gat_W = (const float*)d_in[8];
  const float* gat_as= (const float*)d_in[9];
  const float* gat_an= (const float*)d_in[10];
  const float* gat_b = (const float*)d_in[11];
  const float* Wp    = (const float*)d_in[12];
  const float* Up    = (const float*)d_in[13];
  const float* bp    = (const float*)d_in[14];
  const float* Wb    = (const float*)d_in[15];
  const float* Ub    = (const float*)d_in[16];
  const float* bb    = (const float*)d_in[17];
  const float* Wn    = (const float*)d_in[18];
  const float* Un    = (const float*)d_in[19];
  const float* bn    = (const float*)d_in[20];
  const float* rW1   = (const float*)d_in[21];
  const float* rb1   = (const float*)d_in[22];
  const float* rW2   = (const float*)d_in[23];
  const float* rb2   = (const float*)d_in[24];
  const float* rW3   = (const float*)d_in[25];
  const float* rb3   = (const float*)d_in[26];
  const int* paths   = (const int*)d_in[27];
  const int* seqs    = (const int*)d_in[28];
  const int* nodes   = (const int*)d_in[29];
  const int* adj_idx = (const int*)d_in[30];
  int E = in_sizes[27];

  char* w0 = (char*)d_ws;
  char* w = w0;
  auto alloc = [&](size_t nbytes)->void*{ void* r=(void*)w; w += (nbytes + 255) & ~(size_t)255; return r; };
  float* ns     = (float*)alloc((size_t)NN*DD*4);
  float* gout   = (float*)alloc((size_t)NN*DD*4);
  float* psA    = (float*)alloc((size_t)NP*DD*4);
  float* psB    = (float*)alloc((size_t)NP*DD*4);
  float* xp     = (float*)alloc((size_t)NN*NHD*4);
  float* es     = (float*)alloc((size_t)NN*NH*4);
  float* en     = (float*)alloc((size_t)NN*NH*4);
  float* adjm   = (float*)alloc((size_t)NN*NN*4);
  float* xgp    = (float*)alloc((size_t)NN*G3*4);
  float* xgb    = (float*)alloc((size_t)NN*G3*4);
  float* m2     = (float*)alloc((size_t)NN*DD*4);
  unsigned short* Uthp = (unsigned short*)alloc((size_t)G3*DD*2);
  unsigned short* Utlp = (unsigned short*)alloc((size_t)G3*DD*2);
  unsigned short* Uthb = (unsigned short*)alloc((size_t)G3*DD*2);
  unsigned short* Utlb = (unsigned short*)alloc((size_t)G3*DD*2);
  int* start    = (int*)alloc((size_t)NP*4);
  int* lens     = (int*)alloc((size_t)NP*4);
  int* counts   = (int*)alloc((size_t)NN*4);
  int* offsets  = (int*)alloc((size_t)NN*4);
  int* cursor   = (int*)alloc((size_t)NN*4);
  int* bucket   = (int*)alloc((size_t)E*4);
  float* outF   = (float*)alloc((size_t)E*DD*4);
  char* w_no_outB = w;
  float* outB   = (float*)alloc((size_t)E*DD*4);
  bool fused = ((size_t)(w - w0) <= ws_size);
  if (!fused){ outB = nullptr; w = w_no_outB; }
  (void)n_in; (void)out_size;

  hipMemsetAsync(adjm, 0, (size_t)NN*NN*4, stream);
  hipMemsetAsync(counts, 0, (size_t)NN*4, stream);
  k_init_ns<<<NN,DD,0,stream>>>(ns, qpol, w1, w2, w3, qs);
  k_init_ps<<<(NP*DD+255)/256,256,0,stream>>>(psA, bw, ToS);
  k_adj<<<16,256,0,stream>>>(adjm, adj_idx, lc);
  k_meta<<<(E+255)/256,256,0,stream>>>(paths, seqs, start, lens, E);
  k_count<<<(E+255)/256,256,0,stream>>>(nodes, counts, E);
  k_scan<<<1,NN,0,stream>>>(counts, offsets, cursor);
  k_fill<<<(E+255)/256,256,0,stream>>>(nodes, cursor, bucket, E);
  k_ut<<<(G3*DD+255)/256,256,0,stream>>>(Up, Uthp, Utlp);
  k_ut<<<(G3*DD+255)/256,256,0,stream>>>(Ub, Uthb, Utlb);

  float* ps_cur = psA; float* ps_nxt = psB;
  for (int t=0;t<3;t++){
    k_xp<<<dim3(NN/16, NHD/64),256,0,stream>>>(ns, gat_W, xp);
    k_gat_e<<<dim3(NN,NH),64,0,stream>>>(xp, gat_as, gat_an, es, en);
    k_gat_bias<<<NN,DD,0,stream>>>(gout, gat_b);
    k_attn<<<dim3(NH, NN/32),256,0,stream>>>(xp, es, en, adjm, gout);
    k_xg<<<dim3(NN,3),128,0,stream>>>(gout, Wp, bp, xgp);
    k_xg<<<dim3(NN,3),128,0,stream>>>(gout, Wb, bb, xgb);
    if (fused){
      k_gru2<<<2*(NP/32),512,0,stream>>>(ps_cur, ps_nxt, xgp, xgb, Uthp, Utlp, Uthb, Utlb,
                                         bp+G3, bb+G3, start, lens, nodes, outF, outB, 2);
    } else {
      k_gru2<<<NP/32,512,0,stream>>>(ps_cur, ps_nxt, xgp, xgb, Uthp, Utlp, Uthb, Utlb,
                                     bp+G3, bb+G3, start, lens, nodes, outF, nullptr, 0);
      k_gru2<<<NP/32,512,0,stream>>>(ps_cur, nullptr, xgp, xgb, Uthp, Utlp, Uthb, Utlb,
                                     bp+G3, bb+G3, start, lens, nodes, outF, nullptr, 1);
    }
    k_m2<<<NN,DD,0,stream>>>(outF, outB, counts, offsets, bucket, m2);
    k_ngru<<<NN,DD,0,stream>>>(m2, gout, Wn, Un, bn, ns);
    float* tmp = ps_cur; ps_cur = ps_nxt; ps_nxt = tmp;
  }
  k_read<<<NP/16,256,0,stream>>>(ps_cur, rW1, rb1, rW2, rb2, rW3, rb3, (float*)d_out);
}

// Round 4
// 1687.801 us; speedup vs baseline: 4.7118x; 1.0472x over previous
//
#include <hip/hip_runtime.h>
#include <math.h>

#define NN 512
#define NP 20000
#define DD 128
#define NH 24
#define G3 384
#define NHD 3072  /* NH*DD */

typedef __attribute__((ext_vector_type(8))) short bf8_t;   /* 8 bf16 */
typedef __attribute__((ext_vector_type(4))) float f4_t;
typedef unsigned short ushort_t;

__device__ __forceinline__ float sigf(float x){ return 1.f/(1.f+expf(-x)); }
__device__ __forceinline__ unsigned short f2bf(float f){
  unsigned int u = __float_as_uint(f);
  unsigned int r = (u + 0x7fffu + ((u>>16)&1u)) >> 16;
  return (unsigned short)r;
}
__device__ __forceinline__ float bf2f(unsigned short h){
  return __uint_as_float(((unsigned int)h)<<16);
}

/* ---------------- init ---------------- */
__global__ void k_init_ns(float* ns, const float* qp, const float* w1, const float* w2,
                          const float* w3, const float* qs){
  int n = blockIdx.x, c = threadIdx.x;
  float v = 0.f;
  if (c==0) v=qp[n]; else if (c==1) v=w1[n]; else if (c==2) v=w2[n]; else if (c==3) v=w3[n];
  else if (c<7) v=qs[n*3 + (c-4)];
  ns[n*DD+c]=v;
}

__global__ void k_init_ps(float* ps, const float* bw, const float* tos){
  int i = blockIdx.x*256 + threadIdx.x;
  if (i >= NP*DD) return;
  int p = i>>7, c = i&127;
  float v=0.f; if(c==0) v=bw[p]; else if(c==1) v=tos[p];
  ps[i]=v;
}

__global__ void k_adj(float* adjm, const int* idx, const float* lc){
  int l = blockIdx.x*256+threadIdx.x; if(l>=4096) return;
  adjm[idx[l]] = (lc[l]!=0.f)?1.f:0.f;
}

__global__ void k_meta(const int* paths, const int* seqs, int* start, int* lens, int E){
  int e = blockIdx.x*256+threadIdx.x; if(e>=E) return;
  int p=paths[e], s=seqs[e];
  if (s==0) start[p]=e;
  if (e==E-1 || paths[e+1]!=p) lens[p]=s+1;
}

__global__ void k_count(const int* nodes, int* counts, int E){
  int e = blockIdx.x*256+threadIdx.x; if(e>=E) return;
  atomicAdd(&counts[nodes[e]],1);
}

__global__ void k_scan(const int* counts, int* offsets, int* cursor){
  __shared__ int sh[NN];
  int t=threadIdx.x; int v=counts[t]; sh[t]=v; __syncthreads();
  for (int d=1; d<NN; d<<=1){
    int u = (t>=d)? sh[t-d] : 0;
    __syncthreads();
    sh[t]+=u;
    __syncthreads();
  }
  int ex = sh[t]-v;
  offsets[t]=ex; cursor[t]=ex;
}

__global__ void k_fill(const int* nodes, int* cursor, int* bucket, int E){
  int e = blockIdx.x*256+threadIdx.x; if(e>=E) return;
  int pos = atomicAdd(&cursor[nodes[e]],1);
  bucket[pos]=e;
}

/* ---- length sort (counting sort, descending length) ---- */
__global__ void k_lcount(const int* __restrict__ lens, int* lcnt){
  int p = blockIdx.x*256+threadIdx.x; if(p>=NP) return;
  atomicAdd(&lcnt[lens[p]],1);
}
__global__ void k_lscan(const int* __restrict__ lcnt, int* loff, int* lcur){
  if (threadIdx.x==0){
    int acc=0;
    for (int L=15; L>=0; --L){ loff[L]=acc; lcur[L]=acc; acc+=lcnt[L]; }
  }
}
__global__ void k_lfill(const int* __restrict__ lens, int* lcur, int* perm){
  int p = blockIdx.x*256+threadIdx.x; if(p>=NP) return;
  int pos = atomicAdd(&lcur[lens[p]],1);
  perm[pos]=p;
}

/* build transposed split-bf16 U: Ut[col][k], col 0..383, k 0..127 */
__global__ void k_ut(const float* __restrict__ U, unsigned short* __restrict__ Uth,
                     unsigned short* __restrict__ Utl){
  int i = blockIdx.x*256 + threadIdx.x;
  if (i >= G3*DD) return;
  int col = i >> 7, k = i & 127;
  float v = U[(size_t)k*G3 + col];
  unsigned short h = f2bf(v);
  float rf = v - bf2f(h);
  Uth[i] = h; Utl[i] = f2bf(rf);
}

/* generic transpose+split: W [K][ncols] -> Wt hi/lo [ncols][K], K = 1<<shift */
__global__ void k_wsplit(const float* __restrict__ W, ushort_t* __restrict__ Wh,
                         ushort_t* __restrict__ Wl, int shift, int ncols, int total){
  int i = blockIdx.x*256 + threadIdx.x;
  if (i >= total) return;
  int col = i >> shift, k = i & ((1<<shift)-1);
  float v = W[(size_t)k*ncols + col];
  ushort_t h = f2bf(v);
  Wh[i] = h; Wl[i] = f2bf(v - bf2f(h));
}

/* ---------------- GAT ---------------- */
__global__ __launch_bounds__(256) void k_xp(const float* __restrict__ ns,
                                            const float* __restrict__ W,
                                            float* __restrict__ xp){
  __shared__ float A[16][130];
  int r0 = blockIdx.x*16, c0 = blockIdx.y*64;
  int tid = threadIdx.x;
  for (int idx=tid; idx<16*128; idx+=256){ int r=idx>>7,k=idx&127; A[r][k]=ns[(r0+r)*DD+k]; }
  __syncthreads();
  int cc = c0 + (tid&63); int rq = tid>>6;
  float a0=0.f,a1=0.f,a2=0.f,a3=0.f;
  for (int k=0;k<128;k++){
    float b = W[(size_t)k*NHD + cc];
    a0 += A[rq*4+0][k]*b; a1 += A[rq*4+1][k]*b; a2 += A[rq*4+2][k]*b; a3 += A[rq*4+3][k]*b;
  }
  xp[(size_t)(r0+rq*4+0)*NHD+cc]=a0;
  xp[(size_t)(r0+rq*4+1)*NHD+cc]=a1;
  xp[(size_t)(r0+rq*4+2)*NHD+cc]=a2;
  xp[(size_t)(r0+rq*4+3)*NHD+cc]=a3;
}

__global__ void k_gat_e(const float* __restrict__ xp, const float* __restrict__ as_,
                        const float* __restrict__ an_, float* es, float* en){
  int n = blockIdx.x, h = blockIdx.y, t = threadIdx.x; /* 64 threads */
  const float* xr = xp + ((size_t)n*NH + h)*DD;
  const float* ar = as_ + h*DD; const float* br = an_ + h*DD;
  float s1 = xr[t]*ar[t] + xr[t+64]*ar[t+64];
  float s2 = xr[t]*br[t] + xr[t+64]*br[t+64];
  for (int o=32;o>0;o>>=1){ s1 += __shfl_down(s1,o); s2 += __shfl_down(s2,o); }
  if (t==0){ es[n*NH+h]=s1; en[n*NH+h]=s2; }
}

__global__ void k_gat_bias(float* gout, const float* gb){
  int n = blockIdx.x, c = threadIdx.x;
  gout[n*DD+c] = gb[c];
}

__global__ __launch_bounds__(256) void k_attn(const float* __restrict__ xp,
                      const float* __restrict__ es, const float* __restrict__ en,
                      const float* __restrict__ adjm, float* __restrict__ gout){
  __shared__ float lg[32][513];
  __shared__ float mxs[32], isms[32];
  int h = blockIdx.x, it = blockIdx.y; int i0 = it*32; int tid = threadIdx.x;
  for (int idx=tid; idx<32*512; idx+=256){
    int ii = idx>>9, j = idx&511;
    float l = es[(i0+ii)*NH+h] + en[j*NH+h];
    l = (l>=0.f)? l : 0.2f*l;
    if (adjm[(size_t)(i0+ii)*NN + j]==0.f) l = -1000000000.0f;
    lg[ii][j] = l;
  }
  __syncthreads();
  {
    int t8 = tid&7, ii = tid>>3;
    float m = -INFINITY;
    for (int j=t8;j<512;j+=8) m = fmaxf(m, lg[ii][j]);
    for (int o=4;o>0;o>>=1) m = fmaxf(m, __shfl_xor(m, o));
    float s=0.f;
    for (int j=t8;j<512;j+=8) s += expf(lg[ii][j]-m);
    for (int o=4;o>0;o>>=1) s += __shfl_xor(s,o);
    if (t8==0){ mxs[ii]=m; isms[ii]=1.f/s; }
  }
  __syncthreads();
  for (int idx=tid; idx<32*512; idx+=256){
    int ii = idx>>9, j = idx&511;
    lg[ii][j] = expf(lg[ii][j]-mxs[ii])*isms[ii];
  }
  __syncthreads();
  int cq = tid&31, iq = tid>>5; int c = cq*4;
  float4 acc0=make_float4(0,0,0,0), acc1=acc0, acc2=acc0, acc3=acc0;
  for (int j=0;j<512;j++){
    const float4 xv = *(const float4*)(xp + ((size_t)j*NH + h)*DD + c);
    float p0 = lg[iq*4+0][j], p1 = lg[iq*4+1][j], p2 = lg[iq*4+2][j], p3 = lg[iq*4+3][j];
    acc0.x+=p0*xv.x; acc0.y+=p0*xv.y; acc0.z+=p0*xv.z; acc0.w+=p0*xv.w;
    acc1.x+=p1*xv.x; acc1.y+=p1*xv.y; acc1.z+=p1*xv.z; acc1.w+=p1*xv.w;
    acc2.x+=p2*xv.x; acc2.y+=p2*xv.y; acc2.z+=p2*xv.z; acc2.w+=p2*xv.w;
    acc3.x+=p3*xv.x; acc3.y+=p3*xv.y; acc3.z+=p3*xv.z; acc3.w+=p3*xv.w;
  }
  const float inv = 1.f/24.f;
  float* o0 = gout + (size_t)(i0+iq*4+0)*DD + c;
  float* o1 = gout + (size_t)(i0+iq*4+1)*DD + c;
  float* o2 = gout + (size_t)(i0+iq*4+2)*DD + c;
  float* o3 = gout + (size_t)(i0+iq*4+3)*DD + c;
  atomicAdd(o0+0,acc0.x*inv); atomicAdd(o0+1,acc0.y*inv); atomicAdd(o0+2,acc0.z*inv); atomicAdd(o0+3,acc0.w*inv);
  atomicAdd(o1+0,acc1.x*inv); atomicAdd(o1+1,acc1.y*inv); atomicAdd(o1+2,acc1.z*inv); atomicAdd(o1+3,acc1.w*inv);
  atomicAdd(o2+0,acc2.x*inv); atomicAdd(o2+1,acc2.y*inv); atomicAdd(o2+2,acc2.z*inv); atomicAdd(o2+3,acc2.w*inv);
  atomicAdd(o3+0,acc3.x*inv); atomicAdd(o3+1,acc3.y*inv); atomicAdd(o3+2,acc3.z*inv); atomicAdd(o3+3,acc3.w*inv);
}

__global__ void k_xg(const float* __restrict__ gout, const float* __restrict__ W,
                     const float* __restrict__ b0, float* __restrict__ out){
  int n = blockIdx.x; int j = blockIdx.y*128 + threadIdx.x;
  const float* g = gout + (size_t)n*DD;
  float acc = b0[j];
  for (int k=0;k<128;k++) acc += g[k]*W[(size_t)k*G3 + j];
  out[(size_t)n*G3+j] = acc;
}

/* ---------------- fused bidirectional path GRU (split-bf16 MFMA) ----------------
   Paths are length-sorted (descending) via perm; block step loop runs to the
   block max length Ls[0]. */
__global__ __launch_bounds__(512) void k_gru2(
    const float* __restrict__ ps_in, float* __restrict__ ps_out,
    const float* __restrict__ xgF, const float* __restrict__ xgB,
    const ushort_t* __restrict__ UthF, const ushort_t* __restrict__ UtlF,
    const ushort_t* __restrict__ UthB, const ushort_t* __restrict__ UtlB,
    const float* __restrict__ b1F, const float* __restrict__ b1B,
    const int* __restrict__ start, const int* __restrict__ lens,
    const int* __restrict__ nodes, const int* __restrict__ perm,
    float* __restrict__ outF, float* __restrict__ outB, int mode)
{
  __shared__ __align__(16) ushort_t HsH[2][32][136];
  __shared__ __align__(16) ushort_t HsL[2][32][136];
  __shared__ int Ls[32], Ss[32], Pid[32];
  __shared__ int nid_l[32][8];

  int dir, pblk;
  if (mode==2){ dir = blockIdx.x & 1; pblk = blockIdx.x >> 1; }
  else        { dir = mode;           pblk = blockIdx.x; }
  const bool rev = (dir==1);
  const float* xg = rev ? xgB : xgF;
  const ushort_t* Uth = rev ? UthB : UthF;
  const ushort_t* Utl = rev ? UtlB : UtlF;
  const float* b1 = rev ? b1B : b1F;
  float* ob = (mode==2) ? (rev ? outB : outF) : outF;
  const bool accum = (mode==1);
  float* psn = rev ? (float*)0 : ps_out;

  int pb = pblk*32;
  int tid = threadIdx.x;
  int w = tid>>6, l = tid&63;
  int lr = l&15, lg = l>>4;
  int c = w*16 + lr;

  if (tid<32){ int pid = perm[pb+tid]; Pid[tid]=pid; Ls[tid]=lens[pid]; Ss[tid]=start[pid]; }
  __syncthreads();
  for (int idx=tid; idx<32*128; idx+=512){
    int pp=idx>>7, kk=idx&127;
    float v = ps_in[(size_t)Pid[pp]*DD+kk];
    ushort_t hi = f2bf(v);
    HsH[0][pp][kk]=hi; HsL[0][pp][kk]=f2bf(v - bf2f(hi));
  }
  if (tid<256){
    int p=tid>>3, s=tid&7; int L=Ls[p];
    int nid = 0;
    if (s<L){ int pos = rev ? (L-1-s) : s; nid = nodes[Ss[p]+pos]; }
    nid_l[p][s]=nid;
  }
  __syncthreads();

  int Lmax = Ls[0];  /* descending sort -> first row has block max */
  int Lv[8], Sv[8];
  #pragma unroll
  for (int i=0;i<8;i++){ int p=(i>>2)*16 + lg*4 + (i&3); Lv[i]=Ls[p]; Sv[i]=Ss[p]; }
  float b1z = b1[c], b1r = b1[128+c], b1h = b1[256+c];

  int cur = 0;
  for (int s=0;s<Lmax;s++){
    int nxt = cur^1;
    bool act[8]; int e_[8]; float xzv[8], xrv[8], xhv[8];
    #pragma unroll
    for (int i=0;i<8;i++){
      int p=(i>>2)*16 + lg*4 + (i&3);
      act[i] = (s < Lv[i]);
      int pos = rev ? (Lv[i]-1-s) : s;
      e_[i] = Sv[i] + pos;
      int nid = nid_l[p][s];
      const float* xr = xg + (size_t)nid*G3;
      xzv[i]=xr[c]; xrv[i]=xr[128+c]; xhv[i]=xr[256+c];
    }
    f4_t accz0=(f4_t)(0.f), accz1=(f4_t)(0.f);
    f4_t accr0=(f4_t)(0.f), accr1=(f4_t)(0.f);
    f4_t acch0=(f4_t)(0.f), acch1=(f4_t)(0.f);
    #pragma unroll
    for (int kt=0; kt<4; kt++){
      int kof = kt*32 + lg*8;
      const bf8_t Ahi0 = *(const bf8_t*)&HsH[cur][lr][kof];
      const bf8_t Alo0 = *(const bf8_t*)&HsL[cur][lr][kof];
      const bf8_t Ahi1 = *(const bf8_t*)&HsH[cur][16+lr][kof];
      const bf8_t Alo1 = *(const bf8_t*)&HsL[cur][16+lr][kof];
      const bf8_t Bhz = *(const bf8_t*)(Uth + ((size_t)(      c))*128 + kof);
      const bf8_t Blz = *(const bf8_t*)(Utl + ((size_t)(      c))*128 + kof);
      const bf8_t Bhr = *(const bf8_t*)(Uth + ((size_t)(128 + c))*128 + kof);
      const bf8_t Blr = *(const bf8_t*)(Utl + ((size_t)(128 + c))*128 + kof);
      const bf8_t Bhh = *(const bf8_t*)(Uth + ((size_t)(256 + c))*128 + kof);
      const bf8_t Blh = *(const bf8_t*)(Utl + ((size_t)(256 + c))*128 + kof);
      accz0 = __builtin_amdgcn_mfma_f32_16x16x32_bf16(Ahi0, Bhz, accz0, 0,0,0);
      accz0 = __builtin_amdgcn_mfma_f32_16x16x32_bf16(Alo0, Bhz, accz0, 0,0,0);
      accz0 = __builtin_amdgcn_mfma_f32_16x16x32_bf16(Ahi0, Blz, accz0, 0,0,0);
      accz1 = __builtin_amdgcn_mfma_f32_16x16x32_bf16(Ahi1, Bhz, accz1, 0,0,0);
      accz1 = __builtin_amdgcn_mfma_f32_16x16x32_bf16(Alo1, Bhz, accz1, 0,0,0);
      accz1 = __builtin_amdgcn_mfma_f32_16x16x32_bf16(Ahi1, Blz, accz1, 0,0,0);
      accr0 = __builtin_amdgcn_mfma_f32_16x16x32_bf16(Ahi0, Bhr, accr0, 0,0,0);
      accr0 = __builtin_amdgcn_mfma_f32_16x16x32_bf16(Alo0, Bhr, accr0, 0,0,0);
      accr0 = __builtin_amdgcn_mfma_f32_16x16x32_bf16(Ahi0, Blr, accr0, 0,0,0);
      accr1 = __builtin_amdgcn_mfma_f32_16x16x32_bf16(Ahi1, Bhr, accr1, 0,0,0);
      accr1 = __builtin_amdgcn_mfma_f32_16x16x32_bf16(Alo1, Bhr, accr1, 0,0,0);
      accr1 = __builtin_amdgcn_mfma_f32_16x16x32_bf16(Ahi1, Blr, accr1, 0,0,0);
      acch0 = __builtin_amdgcn_mfma_f32_16x16x32_bf16(Ahi0, Bhh, acch0, 0,0,0);
      acch0 = __builtin_amdgcn_mfma_f32_16x16x32_bf16(Alo0, Bhh, acch0, 0,0,0);
      acch0 = __builtin_amdgcn_mfma_f32_16x16x32_bf16(Ahi0, Blh, acch0, 0,0,0);
      acch1 = __builtin_amdgcn_mfma_f32_16x16x32_bf16(Ahi1, Bhh, acch1, 0,0,0);
      acch1 = __builtin_amdgcn_mfma_f32_16x16x32_bf16(Alo1, Bhh, acch1, 0,0,0);
      acch1 = __builtin_amdgcn_mfma_f32_16x16x32_bf16(Ahi1, Blh, acch1, 0,0,0);
    }
#define EPI(i, mt, qq, AZ, AR, AH) { \
    int p = (mt)*16 + lg*4 + (qq); \
    if (act[i]) { \
      float hold = bf2f(HsH[cur][p][c]) + bf2f(HsL[cur][p][c]); \
      float z = sigf(xzv[i] + (AZ) + b1z); \
      float r = sigf(xrv[i] + (AR) + b1r); \
      float hc = tanhf(xhv[i] + r*((AH) + b1h)); \
      float hn = z*hold + (1.f-z)*hc; \
      ushort_t hi2 = f2bf(hn); \
      HsH[nxt][p][c]=hi2; HsL[nxt][p][c]=f2bf(hn - bf2f(hi2)); \
      float* o = ob + (size_t)e_[i]*DD + c; \
      if (accum) *o += hn; else *o = hn; \
    } else { \
      HsH[nxt][p][c]=HsH[cur][p][c]; HsL[nxt][p][c]=HsL[cur][p][c]; \
    } }
    EPI(0,0,0, accz0.x, accr0.x, acch0.x)
    EPI(1,0,1, accz0.y, accr0.y, acch0.y)
    EPI(2,0,2, accz0.z, accr0.z, acch0.z)
    EPI(3,0,3, accz0.w, accr0.w, acch0.w)
    EPI(4,1,0, accz1.x, accr1.x, acch1.x)
    EPI(5,1,1, accz1.y, accr1.y, acch1.y)
    EPI(6,1,2, accz1.z, accr1.z, acch1.z)
    EPI(7,1,3, accz1.w, accr1.w, acch1.w)
#undef EPI
    __syncthreads();
    cur = nxt;
  }
  if (psn){
    for (int idx=tid; idx<32*128; idx+=512){
      int pp=idx>>7, kk=idx&127;
      psn[(size_t)Pid[pp]*DD+kk] = bf2f(HsH[cur][pp][kk]) + bf2f(HsL[cur][pp][kk]);
    }
  }
}

/* ---------------- m2 + node GRU ---------------- */
__global__ void k_m2(const float* __restrict__ outF, const float* __restrict__ outB,
                     const int* __restrict__ counts,
                     const int* __restrict__ offsets, const int* __restrict__ bucket,
                     float* __restrict__ m2){
  int n = blockIdx.x; int c = threadIdx.x; /* 128 threads */
  int cnt = counts[n], off = offsets[n];
  float acc = 0.f;
  if (outB){
    for (int idx=0; idx<cnt; ++idx){
      int e = bucket[off+idx];
      acc += outF[(size_t)e*DD + c] + outB[(size_t)e*DD + c];
    }
  } else {
    for (int idx=0; idx<cnt; ++idx){
      int e = bucket[off+idx];
      acc += outF[(size_t)e*DD + c];
    }
  }
  m2[n*DD+c] = acc;
}

__global__ void k_ngru(const float* __restrict__ m2, const float* __restrict__ gout,
                       const float* __restrict__ Wn, const float* __restrict__ Un,
                       const float* __restrict__ bn, float* __restrict__ ns){
  int n = blockIdx.x, c = threadIdx.x; /* 128 threads */
  float xz=0.f,xr=0.f,xh=0.f,hz=0.f,hr=0.f,hh=0.f;
  const float* x = m2 + (size_t)n*DD; const float* h = gout + (size_t)n*DD;
  for (int k=0;k<128;k++){
    float xk=x[k], hk=h[k];
    const float* wr = Wn + (size_t)k*G3; const float* ur = Un + (size_t)k*G3;
    xz += xk*wr[c]; xr += xk*wr[128+c]; xh += xk*wr[256+c];
    hz += hk*ur[c]; hr += hk*ur[128+c]; hh += hk*ur[256+c];
  }
  float z = sigf(xz+bn[c]     + hz+bn[G3+c]);
  float r = sigf(xr+bn[128+c] + hr+bn[G3+128+c]);
  float hc = tanhf(xh+bn[256+c] + r*(hh+bn[G3+256+c]));
  ns[n*DD+c] = z*h[c] + (1.f-z)*hc;
}

/* ---------------- MFMA readout ----------------
   layer1: X(32x128)@rW1(128x256) selu; layer2: @rW2(256x256) relu; layer3: @rW3.
   8 waves; wave w owns cols w*32..w*32+31 (two 16-col tiles), rows 0..31. */
__global__ __launch_bounds__(512) void k_read2(
    const float* __restrict__ ps,
    const ushort_t* __restrict__ r1h, const ushort_t* __restrict__ r1l,
    const ushort_t* __restrict__ r2h, const ushort_t* __restrict__ r2l,
    const float* __restrict__ rb1, const float* __restrict__ rb2,
    const float* __restrict__ rW3, const float* __restrict__ rb3,
    float* __restrict__ out)
{
  __shared__ __align__(16) ushort_t XsH[32][136], XsL[32][136];
  __shared__ __align__(16) char buf[32*264*2*2];   /* H1 hi/lo; later reused as H2 fp32 */
  ushort_t (*H1H)[264] = (ushort_t(*)[264])buf;
  ushort_t (*H1L)[264] = (ushort_t(*)[264])(buf + 32*264*2);
  float (*H2)[257] = (float(*)[257])buf;
  int pb = blockIdx.x*32, tid = threadIdx.x;
  int w = tid>>6, l = tid&63, lr = l&15, lg = l>>4;
  for (int idx=tid; idx<32*128; idx+=512){
    int pp=idx>>7, kk=idx&127;
    float v = ps[(size_t)(pb+pp)*DD+kk];
    ushort_t hi=f2bf(v); XsH[pp][kk]=hi; XsL[pp][kk]=f2bf(v-bf2f(hi));
  }
  __syncthreads();
  int col0 = w*32 + lr, col1 = col0 + 16;
  /* layer 1 */
  f4_t a00=(f4_t)(0.f), a01=(f4_t)(0.f), a10=(f4_t)(0.f), a11=(f4_t)(0.f);
  #pragma unroll
  for (int kt=0; kt<4; kt++){
    int kof = kt*32 + lg*8;
    const bf8_t Ah0 = *(const bf8_t*)&XsH[lr][kof];
    const bf8_t Al0 = *(const bf8_t*)&XsL[lr][kof];
    const bf8_t Ah1 = *(const bf8_t*)&XsH[16+lr][kof];
    const bf8_t Al1 = *(const bf8_t*)&XsL[16+lr][kof];
    const bf8_t B0h = *(const bf8_t*)(r1h + (size_t)col0*128 + kof);
    const bf8_t B0l = *(const bf8_t*)(r1l + (size_t)col0*128 + kof);
    const bf8_t B1h = *(const bf8_t*)(r1h + (size_t)col1*128 + kof);
    const bf8_t B1l = *(const bf8_t*)(r1l + (size_t)col1*128 + kof);
    a00 = __builtin_amdgcn_mfma_f32_16x16x32_bf16(Ah0,B0h,a00,0,0,0);
    a00 = __builtin_amdgcn_mfma_f32_16x16x32_bf16(Al0,B0h,a00,0,0,0);
    a00 = __builtin_amdgcn_mfma_f32_16x16x32_bf16(Ah0,B0l,a00,0,0,0);
    a01 = __builtin_amdgcn_mfma_f32_16x16x32_bf16(Ah0,B1h,a01,0,0,0);
    a01 = __builtin_amdgcn_mfma_f32_16x16x32_bf16(Al0,B1h,a01,0,0,0);
    a01 = __builtin_amdgcn_mfma_f32_16x16x32_bf16(Ah0,B1l,a01,0,0,0);
    a10 = __builtin_amdgcn_mfma_f32_16x16x32_bf16(Ah1,B0h,a10,0,0,0);
    a10 = __builtin_amdgcn_mfma_f32_16x16x32_bf16(Al1,B0h,a10,0,0,0);
    a10 = __builtin_amdgcn_mfma_f32_16x16x32_bf16(Ah1,B0l,a10,0,0,0);
    a11 = __builtin_amdgcn_mfma_f32_16x16x32_bf16(Ah1,B1h,a11,0,0,0);
    a11 = __builtin_amdgcn_mfma_f32_16x16x32_bf16(Al1,B1h,a11,0,0,0);
    a11 = __builtin_amdgcn_mfma_f32_16x16x32_bf16(Ah1,B1l,a11,0,0,0);
  }
  float rb1c0 = rb1[col0], rb1c1 = rb1[col1];
  #pragma unroll
  for (int q=0;q<4;q++){
    int row0 = lg*4+q, row1 = 16+lg*4+q;
    float v00 = a00[q]+rb1c0, v01 = a01[q]+rb1c1, v10 = a10[q]+rb1c0, v11 = a11[q]+rb1c1;
    v00 = 1.0507009873554805f * (v00>0.f ? v00 : 1.6732632423543772f*expm1f(v00));
    v01 = 1.0507009873554805f * (v01>0.f ? v01 : 1.6732632423543772f*expm1f(v01));
    v10 = 1.0507009873554805f * (v10>0.f ? v10 : 1.6732632423543772f*expm1f(v10));
    v11 = 1.0507009873554805f * (v11>0.f ? v11 : 1.6732632423543772f*expm1f(v11));
    ushort_t h;
    h=f2bf(v00); H1H[row0][col0]=h; H1L[row0][col0]=f2bf(v00-bf2f(h));
    h=f2bf(v01); H1H[row0][col1]=h; H1L[row0][col1]=f2bf(v01-bf2f(h));
    h=f2bf(v10); H1H[row1][col0]=h; H1L[row1][col0]=f2bf(v10-bf2f(h));
    h=f2bf(v11); H1H[row1][col1]=h; H1L[row1][col1]=f2bf(v11-bf2f(h));
  }
  __syncthreads();
  /* layer 2 (K=256) */
  f4_t c00=(f4_t)(0.f), c01=(f4_t)(0.f), c10=(f4_t)(0.f), c11=(f4_t)(0.f);
  #pragma unroll
  for (int kt=0; kt<8; kt++){
    int kof = kt*32 + lg*8;
    const bf8_t Ah0 = *(const bf8_t*)&H1H[lr][kof];
    const bf8_t Al0 = *(const bf8_t*)&H1L[lr][kof];
    const bf8_t Ah1 = *(const bf8_t*)&H1H[16+lr][kof];
    const bf8_t Al1 = *(const bf8_t*)&H1L[16+lr][kof];
    const bf8_t B0h = *(const bf8_t*)(r2h + (size_t)col0*256 + kof);
    const bf8_t B0l = *(const bf8_t*)(r2l + (size_t)col0*256 + kof);
    const bf8_t B1h = *(const bf8_t*)(r2h + (size_t)col1*256 + kof);
    const bf8_t B1l = *(const bf8_t*)(r2l + (size_t)col1*256 + kof);
    c00 = __builtin_amdgcn_mfma_f32_16x16x32_bf16(Ah0,B0h,c00,0,0,0);
    c00 = __builtin_amdgcn_mfma_f32_16x16x32_bf16(Al0,B0h,c00,0,0,0);
    c00 = __builtin_amdgcn_mfma_f32_16x16x32_bf16(Ah0,B0l,c00,0,0,0);
    c01 = __builtin_amdgcn_mfma_f32_16x16x32_bf16(Ah0,B1h,c01,0,0,0);
    c01 = __builtin_amdgcn_mfma_f32_16x16x32_bf16(Al0,B1h,c01,0,0,0);
    c01 = __builtin_amdgcn_mfma_f32_16x16x32_bf16(Ah0,B1l,c01,0,0,0);
    c10 = __builtin_amdgcn_mfma_f32_16x16x32_bf16(Ah1,B0h,c10,0,0,0);
    c10 = __builtin_amdgcn_mfma_f32_16x16x32_bf16(Al1,B0h,c10,0,0,0);
    c10 = __builtin_amdgcn_mfma_f32_16x16x32_bf16(Ah1,B0l,c10,0,0,0);
    c11 = __builtin_amdgcn_mfma_f32_16x16x32_bf16(Ah1,B1h,c11,0,0,0);
    c11 = __builtin_amdgcn_mfma_f32_16x16x32_bf16(Al1,B1h,c11,0,0,0);
    c11 = __builtin_amdgcn_mfma_f32_16x16x32_bf16(Ah1,B1l,c11,0,0,0);
  }
  __syncthreads();   /* all H1 reads done before aliasing with H2 */
  float rb2c0 = rb2[col0], rb2c1 = rb2[col1];
  #pragma unroll
  for (int q=0;q<4;q++){
    int row0 = lg*4+q, row1 = 16+lg*4+q;
    H2[row0][col0] = fmaxf(c00[q]+rb2c0, 0.f);
    H2[row0][col1] = fmaxf(c01[q]+rb2c1, 0.f);
    H2[row1][col0] = fmaxf(c10[q]+rb2c0, 0.f);
    H2[row1][col1] = fmaxf(c11[q]+rb2c1, 0.f);
  }
  __syncthreads();
  /* layer 3: row r = tid>>4, 16 lanes per row */
  int r = tid>>4, j0 = tid&15;
  float s = 0.f;
  for (int j=j0; j<256; j+=16) s += H2[r][j]*rW3[j];
  for (int o=8;o>0;o>>=1) s += __shfl_xor(s,o);
  if (j0==0) out[pb+r] = s + rb3[0];
}

/* ---------------- host ---------------- */
extern "C" void kernel_launch(void* const* d_in, const int* in_sizes, int n_in,
                              void* d_out, int out_size, void* d_ws, size_t ws_size,
                              hipStream_t stream)
{
  const float* ToS   = (const float*)d_in[0];
  const float* bw    = (const float*)d_in[1];
  const float* qpol  = (const float*)d_in[2];
  const float* w1    = (const float*)d_in[3];
  const float* w2    = (const float*)d_in[4];
  const float* w3    = (const float*)d_in[5];
  const float* qs    = (const float*)d_in[6];
  const float* lc    = (const float*)d_in[7];
  const float* gat_W = (const float*)d_in[8];
  const float* gat_as= (const float*)d_in[9];
  const float* gat_an= (const float*)d_in[10];
  const float* gat_b = (const float*)d_in[11];
  const float* Wp    = (const float*)d_in[12];
  const float* Up    = (const float*)d_in[13];
  const float* bp    = (const float*)d_in[14];
  const float* Wb    = (const float*)d_in[15];
  const float* Ub    = (const float*)d_in[16];
  const float* bb    = (const float*)d_in[17];
  const float* Wn    = (const float*)d_in[18];
  const float* Un    = (const float*)d_in[19];
  const float* bn    = (const float*)d_in[20];
  const float* rW1   = (const float*)d_in[21];
  const float* rb1   = (const float*)d_in[22];
  const float* rW2   = (const float*)d_in[23];
  const float* rb2   = (const float*)d_in[24];
  const float* rW3   = (const float*)d_in[25];
  const float* rb3   = (const float*)d_in[26];
  const int* paths   = (const int*)d_in[27];
  const int* seqs    = (const int*)d_in[28];
  const int* nodes   = (const int*)d_in[29];
  const int* adj_idx = (const int*)d_in[30];
  int E = in_sizes[27];

  char* w0 = (char*)d_ws;
  char* w = w0;
  auto alloc = [&](size_t nbytes)->void*{ void* r=(void*)w; w += (nbytes + 255) & ~(size_t)255; return r; };
  float* ns     = (float*)alloc((size_t)NN*DD*4);
  float* gout   = (float*)alloc((size_t)NN*DD*4);
  float* psA    = (float*)alloc((size_t)NP*DD*4);
  float* psB    = (float*)alloc((size_t)NP*DD*4);
  float* xp     = (float*)alloc((size_t)NN*NHD*4);
  float* es     = (float*)alloc((size_t)NN*NH*4);
  float* en     = (float*)alloc((size_t)NN*NH*4);
  float* adjm   = (float*)alloc((size_t)NN*NN*4);
  float* xgp    = (float*)alloc((size_t)NN*G3*4);
  float* xgb    = (float*)alloc((size_t)NN*G3*4);
  float* m2     = (float*)alloc((size_t)NN*DD*4);
  unsigned short* Uthp = (unsigned short*)alloc((size_t)G3*DD*2);
  unsigned short* Utlp = (unsigned short*)alloc((size_t)G3*DD*2);
  unsigned short* Uthb = (unsigned short*)alloc((size_t)G3*DD*2);
  unsigned short* Utlb = (unsigned short*)alloc((size_t)G3*DD*2);
  ushort_t* r1h = (ushort_t*)alloc((size_t)256*128*2);
  ushort_t* r1l = (ushort_t*)alloc((size_t)256*128*2);
  ushort_t* r2h = (ushort_t*)alloc((size_t)256*256*2);
  ushort_t* r2l = (ushort_t*)alloc((size_t)256*256*2);
  int* start    = (int*)alloc((size_t)NP*4);
  int* lens     = (int*)alloc((size_t)NP*4);
  int* counts   = (int*)alloc((size_t)NN*4);
  int* offsets  = (int*)alloc((size_t)NN*4);
  int* cursor   = (int*)alloc((size_t)NN*4);
  int* perm     = (int*)alloc((size_t)NP*4);
  int* lcnt     = (int*)alloc(16*4);
  int* loff     = (int*)alloc(16*4);
  int* lcur     = (int*)alloc(16*4);
  int* bucket   = (int*)alloc((size_t)E*4);
  float* outF   = (float*)alloc((size_t)E*DD*4);
  char* w_no_outB = w;
  float* outB   = (float*)alloc((size_t)E*DD*4);
  bool fused = ((size_t)(w - w0) <= ws_size);
  if (!fused){ outB = nullptr; w = w_no_outB; }
  (void)n_in; (void)out_size;

  hipMemsetAsync(adjm, 0, (size_t)NN*NN*4, stream);
  hipMemsetAsync(counts, 0, (size_t)NN*4, stream);
  hipMemsetAsync(lcnt, 0, 16*4, stream);
  k_init_ns<<<NN,DD,0,stream>>>(ns, qpol, w1, w2, w3, qs);
  k_init_ps<<<(NP*DD+255)/256,256,0,stream>>>(psA, bw, ToS);
  k_adj<<<16,256,0,stream>>>(adjm, adj_idx, lc);
  k_meta<<<(E+255)/256,256,0,stream>>>(paths, seqs, start, lens, E);
  k_count<<<(E+255)/256,256,0,stream>>>(nodes, counts, E);
  k_scan<<<1,NN,0,stream>>>(counts, offsets, cursor);
  k_fill<<<(E+255)/256,256,0,stream>>>(nodes, cursor, bucket, E);
  k_lcount<<<(NP+255)/256,256,0,stream>>>(lens, lcnt);
  k_lscan<<<1,64,0,stream>>>(lcnt, loff, lcur);
  k_lfill<<<(NP+255)/256,256,0,stream>>>(lens, lcur, perm);
  k_ut<<<(G3*DD+255)/256,256,0,stream>>>(Up, Uthp, Utlp);
  k_ut<<<(G3*DD+255)/256,256,0,stream>>>(Ub, Uthb, Utlb);
  k_wsplit<<<(256*128+255)/256,256,0,stream>>>(rW1, r1h, r1l, 7, 256, 256*128);
  k_wsplit<<<(256*256+255)/256,256,0,stream>>>(rW2, r2h, r2l, 8, 256, 256*256);

  float* ps_cur = psA; float* ps_nxt = psB;
  for (int t=0;t<3;t++){
    k_xp<<<dim3(NN/16, NHD/64),256,0,stream>>>(ns, gat_W, xp);
    k_gat_e<<<dim3(NN,NH),64,0,stream>>>(xp, gat_as, gat_an, es, en);
    k_gat_bias<<<NN,DD,0,stream>>>(gout, gat_b);
    k_attn<<<dim3(NH, NN/32),256,0,stream>>>(xp, es, en, adjm, gout);
    k_xg<<<dim3(NN,3),128,0,stream>>>(gout, Wp, bp, xgp);
    k_xg<<<dim3(NN,3),128,0,stream>>>(gout, Wb, bb, xgb);
    if (fused){
      k_gru2<<<2*(NP/32),512,0,stream>>>(ps_cur, ps_nxt, xgp, xgb, Uthp, Utlp, Uthb, Utlb,
                                         bp+G3, bb+G3, start, lens, nodes, perm, outF, outB, 2);
    } else {
      k_gru2<<<NP/32,512,0,stream>>>(ps_cur, ps_nxt, xgp, xgb, Uthp, Utlp, Uthb, Utlb,
                                     bp+G3, bb+G3, start, lens, nodes, perm, outF, nullptr, 0);
      k_gru2<<<NP/32,512,0,stream>>>(ps_cur, nullptr, xgp, xgb, Uthp, Utlp, Uthb, Utlb,
                                     bp+G3, bb+G3, start, lens, nodes, perm, outF, nullptr, 1);
    }
    k_m2<<<NN,DD,0,stream>>>(outF, outB, counts, offsets, bucket, m2);
    k_ngru<<<NN,DD,0,stream>>>(m2, gout, Wn, Un, bn, ns);
    float* tmp = ps_cur; ps_cur = ps_nxt; ps_nxt = tmp;
  }
  k_read2<<<NP/32,512,0,stream>>>(ps_cur, r1h, r1l, r2h, r2l, rb1, rb2, rW3, rb3, (float*)d_out);
}

// Round 5
// 1548.167 us; speedup vs baseline: 5.1368x; 1.0902x over previous
//
#include <hip/hip_runtime.h>
#include <math.h>

#define NN 512
#define NP 20000
#define DD 128
#define NH 24
#define G3 384
#define NHD 3072  /* NH*DD */

typedef __attribute__((ext_vector_type(8))) short bf8_t;   /* 8 bf16 */
typedef __attribute__((ext_vector_type(4))) float f4_t;
typedef unsigned short ushort_t;

/* fast transcendentals: v_exp_f32 / v_rcp_f32 based */
__device__ __forceinline__ float sigf(float x){
  return __builtin_amdgcn_rcpf(1.f + __expf(-x));
}
__device__ __forceinline__ float tanh_fast(float x){
  float ax = fabsf(x);
  float e = __expf(-2.f*ax);
  float t = (1.f - e) * __builtin_amdgcn_rcpf(1.f + e);
  return copysignf(t, x);
}
__device__ __forceinline__ unsigned short f2bf(float f){
  unsigned int u = __float_as_uint(f);
  unsigned int r = (u + 0x7fffu + ((u>>16)&1u)) >> 16;
  return (unsigned short)r;
}
__device__ __forceinline__ float bf2f(unsigned short h){
  return __uint_as_float(((unsigned int)h)<<16);
}

/* ---------------- init ---------------- */
__global__ void k_init_ns(float* ns, const float* qp, const float* w1, const float* w2,
                          const float* w3, const float* qs){
  int n = blockIdx.x, c = threadIdx.x;
  float v = 0.f;
  if (c==0) v=qp[n]; else if (c==1) v=w1[n]; else if (c==2) v=w2[n]; else if (c==3) v=w3[n];
  else if (c<7) v=qs[n*3 + (c-4)];
  ns[n*DD+c]=v;
}

__global__ void k_init_ps(float* ps, const float* bw, const float* tos){
  int i = blockIdx.x*256 + threadIdx.x;
  if (i >= NP*DD) return;
  int p = i>>7, c = i&127;
  float v=0.f; if(c==0) v=bw[p]; else if(c==1) v=tos[p];
  ps[i]=v;
}

/* adjacency as bitmask: adjb[i*16 + (j>>5)] bit (j&31) */
__global__ void k_adj(unsigned int* adjb, const int* idx, const float* lc){
  int l = blockIdx.x*256+threadIdx.x; if(l>=4096) return;
  if (lc[l]!=0.f){
    int a = idx[l]; int i = a>>9, j = a&511;
    atomicOr(&adjb[i*16 + (j>>5)], 1u<<(j&31));
  }
}

__global__ void k_meta(const int* paths, const int* seqs, int* start, int* lens, int E){
  int e = blockIdx.x*256+threadIdx.x; if(e>=E) return;
  int p=paths[e], s=seqs[e];
  if (s==0) start[p]=e;
  if (e==E-1 || paths[e+1]!=p) lens[p]=s+1;
}

__global__ void k_count(const int* nodes, int* counts, int E){
  int e = blockIdx.x*256+threadIdx.x; if(e>=E) return;
  atomicAdd(&counts[nodes[e]],1);
}

__global__ void k_scan(const int* counts, int* offsets, int* cursor){
  __shared__ int sh[NN];
  int t=threadIdx.x; int v=counts[t]; sh[t]=v; __syncthreads();
  for (int d=1; d<NN; d<<=1){
    int u = (t>=d)? sh[t-d] : 0;
    __syncthreads();
    sh[t]+=u;
    __syncthreads();
  }
  int ex = sh[t]-v;
  offsets[t]=ex; cursor[t]=ex;
}

__global__ void k_fill(const int* nodes, int* cursor, int* bucket, int E){
  int e = blockIdx.x*256+threadIdx.x; if(e>=E) return;
  int pos = atomicAdd(&cursor[nodes[e]],1);
  bucket[pos]=e;
}

/* ---- length sort (counting sort, descending length) ---- */
__global__ void k_lcount(const int* __restrict__ lens, int* lcnt){
  int p = blockIdx.x*256+threadIdx.x; if(p>=NP) return;
  atomicAdd(&lcnt[lens[p]],1);
}
__global__ void k_lscan(const int* __restrict__ lcnt, int* loff, int* lcur){
  if (threadIdx.x==0){
    int acc=0;
    for (int L=15; L>=0; --L){ loff[L]=acc; lcur[L]=acc; acc+=lcnt[L]; }
  }
}
__global__ void k_lfill(const int* __restrict__ lens, int* lcur, int* perm){
  int p = blockIdx.x*256+threadIdx.x; if(p>=NP) return;
  int pos = atomicAdd(&lcur[lens[p]],1);
  perm[pos]=p;
}

/* build transposed split-bf16 U: Ut[col][k], col 0..383, k 0..127 */
__global__ void k_ut(const float* __restrict__ U, unsigned short* __restrict__ Uth,
                     unsigned short* __restrict__ Utl){
  int i = blockIdx.x*256 + threadIdx.x;
  if (i >= G3*DD) return;
  int col = i >> 7, k = i & 127;
  float v = U[(size_t)k*G3 + col];
  unsigned short h = f2bf(v);
  float rf = v - bf2f(h);
  Uth[i] = h; Utl[i] = f2bf(rf);
}

/* generic transpose+split: W [K][ncols] -> Wt hi/lo [ncols][K], K = 1<<shift */
__global__ void k_wsplit(const float* __restrict__ W, ushort_t* __restrict__ Wh,
                         ushort_t* __restrict__ Wl, int shift, int ncols, int total){
  int i = blockIdx.x*256 + threadIdx.x;
  if (i >= total) return;
  int col = i >> shift, k = i & ((1<<shift)-1);
  float v = W[(size_t)k*ncols + col];
  ushort_t h = f2bf(v);
  Wh[i] = h; Wl[i] = f2bf(v - bf2f(h));
}

/* ---------------- GAT ---------------- */
/* xp = ns @ gat_W via split-bf16 MFMA. grid (NN/32, NHD/256), 512 thr. */
__global__ __launch_bounds__(512) void k_xp2(const float* __restrict__ ns,
                      const ushort_t* __restrict__ gwh, const ushort_t* __restrict__ gwl,
                      float* __restrict__ xp){
  __shared__ __align__(16) ushort_t XsH[32][136], XsL[32][136];
  int r0 = blockIdx.x*32, c0 = blockIdx.y*256;
  int tid = threadIdx.x;
  int w = tid>>6, l = tid&63, lr = l&15, lg = l>>4;
  for (int idx=tid; idx<32*128; idx+=512){
    int pp=idx>>7, kk=idx&127;
    float v = ns[(size_t)(r0+pp)*DD+kk];
    ushort_t hi=f2bf(v); XsH[pp][kk]=hi; XsL[pp][kk]=f2bf(v-bf2f(hi));
  }
  __syncthreads();
  int col0 = c0 + w*32 + lr, col1 = col0 + 16;
  f4_t a00=(f4_t)(0.f), a01=(f4_t)(0.f), a10=(f4_t)(0.f), a11=(f4_t)(0.f);
  #pragma unroll
  for (int kt=0; kt<4; kt++){
    int kof = kt*32 + lg*8;
    const bf8_t Ah0 = *(const bf8_t*)&XsH[lr][kof];
    const bf8_t Al0 = *(const bf8_t*)&XsL[lr][kof];
    const bf8_t Ah1 = *(const bf8_t*)&XsH[16+lr][kof];
    const bf8_t Al1 = *(const bf8_t*)&XsL[16+lr][kof];
    const bf8_t B0h = *(const bf8_t*)(gwh + (size_t)col0*128 + kof);
    const bf8_t B0l = *(const bf8_t*)(gwl + (size_t)col0*128 + kof);
    const bf8_t B1h = *(const bf8_t*)(gwh + (size_t)col1*128 + kof);
    const bf8_t B1l = *(const bf8_t*)(gwl + (size_t)col1*128 + kof);
    a00 = __builtin_amdgcn_mfma_f32_16x16x32_bf16(Ah0,B0h,a00,0,0,0);
    a00 = __builtin_amdgcn_mfma_f32_16x16x32_bf16(Al0,B0h,a00,0,0,0);
    a00 = __builtin_amdgcn_mfma_f32_16x16x32_bf16(Ah0,B0l,a00,0,0,0);
    a01 = __builtin_amdgcn_mfma_f32_16x16x32_bf16(Ah0,B1h,a01,0,0,0);
    a01 = __builtin_amdgcn_mfma_f32_16x16x32_bf16(Al0,B1h,a01,0,0,0);
    a01 = __builtin_amdgcn_mfma_f32_16x16x32_bf16(Ah0,B1l,a01,0,0,0);
    a10 = __builtin_amdgcn_mfma_f32_16x16x32_bf16(Ah1,B0h,a10,0,0,0);
    a10 = __builtin_amdgcn_mfma_f32_16x16x32_bf16(Al1,B0h,a10,0,0,0);
    a10 = __builtin_amdgcn_mfma_f32_16x16x32_bf16(Ah1,B0l,a10,0,0,0);
    a11 = __builtin_amdgcn_mfma_f32_16x16x32_bf16(Ah1,B1h,a11,0,0,0);
    a11 = __builtin_amdgcn_mfma_f32_16x16x32_bf16(Al1,B1h,a11,0,0,0);
    a11 = __builtin_amdgcn_mfma_f32_16x16x32_bf16(Ah1,B1l,a11,0,0,0);
  }
  #pragma unroll
  for (int q=0;q<4;q++){
    int row0 = lg*4+q, row1 = 16+lg*4+q;
    xp[(size_t)(r0+row0)*NHD + col0] = a00[q];
    xp[(size_t)(r0+row0)*NHD + col1] = a01[q];
    xp[(size_t)(r0+row1)*NHD + col0] = a10[q];
    xp[(size_t)(r0+row1)*NHD + col1] = a11[q];
  }
}

__global__ void k_gat_e(const float* __restrict__ xp, const float* __restrict__ as_,
                        const float* __restrict__ an_, float* es, float* en){
  int n = blockIdx.x, h = blockIdx.y, t = threadIdx.x; /* 64 threads */
  const float* xr = xp + ((size_t)n*NH + h)*DD;
  const float* ar = as_ + h*DD; const float* br = an_ + h*DD;
  float s1 = xr[t]*ar[t] + xr[t+64]*ar[t+64];
  float s2 = xr[t]*br[t] + xr[t+64]*br[t+64];
  for (int o=32;o>0;o>>=1){ s1 += __shfl_down(s1,o); s2 += __shfl_down(s2,o); }
  if (t==0){ es[n*NH+h]=s1; en[n*NH+h]=s2; }
}

__global__ void k_gat_bias(float* gout, const float* gb){
  int n = blockIdx.x, c = threadIdx.x;
  gout[n*DD+c] = gb[c];
}

__global__ __launch_bounds__(256) void k_attn(const float* __restrict__ xp,
                      const float* __restrict__ es, const float* __restrict__ en,
                      const unsigned int* __restrict__ adjb, float* __restrict__ gout){
  __shared__ float lg[32][513];
  __shared__ float mxs[32], isms[32];
  int h = blockIdx.x, it = blockIdx.y; int i0 = it*32; int tid = threadIdx.x;
  for (int idx=tid; idx<32*512; idx+=256){
    int ii = idx>>9, j = idx&511;
    float l = es[(i0+ii)*NH+h] + en[j*NH+h];
    l = (l>=0.f)? l : 0.2f*l;
    unsigned int m = adjb[(i0+ii)*16 + (j>>5)];
    if (!((m>>(j&31))&1u)) l = -1000000000.0f;
    lg[ii][j] = l;
  }
  __syncthreads();
  {
    int t8 = tid&7, ii = tid>>3;
    float m = -INFINITY;
    for (int j=t8;j<512;j+=8) m = fmaxf(m, lg[ii][j]);
    for (int o=4;o>0;o>>=1) m = fmaxf(m, __shfl_xor(m, o));
    float s=0.f;
    for (int j=t8;j<512;j+=8) s += __expf(lg[ii][j]-m);
    for (int o=4;o>0;o>>=1) s += __shfl_xor(s,o);
    if (t8==0){ mxs[ii]=m; isms[ii]=__builtin_amdgcn_rcpf(s); }
  }
  __syncthreads();
  for (int idx=tid; idx<32*512; idx+=256){
    int ii = idx>>9, j = idx&511;
    lg[ii][j] = __expf(lg[ii][j]-mxs[ii])*isms[ii];
  }
  __syncthreads();
  int cq = tid&31, iq = tid>>5; int c = cq*4;
  float4 acc0=make_float4(0,0,0,0), acc1=acc0, acc2=acc0, acc3=acc0;
  for (int j=0;j<512;j++){
    const float4 xv = *(const float4*)(xp + ((size_t)j*NH + h)*DD + c);
    float p0 = lg[iq*4+0][j], p1 = lg[iq*4+1][j], p2 = lg[iq*4+2][j], p3 = lg[iq*4+3][j];
    acc0.x+=p0*xv.x; acc0.y+=p0*xv.y; acc0.z+=p0*xv.z; acc0.w+=p0*xv.w;
    acc1.x+=p1*xv.x; acc1.y+=p1*xv.y; acc1.z+=p1*xv.z; acc1.w+=p1*xv.w;
    acc2.x+=p2*xv.x; acc2.y+=p2*xv.y; acc2.z+=p2*xv.z; acc2.w+=p2*xv.w;
    acc3.x+=p3*xv.x; acc3.y+=p3*xv.y; acc3.z+=p3*xv.z; acc3.w+=p3*xv.w;
  }
  const float inv = 1.f/24.f;
  float* o0 = gout + (size_t)(i0+iq*4+0)*DD + c;
  float* o1 = gout + (size_t)(i0+iq*4+1)*DD + c;
  float* o2 = gout + (size_t)(i0+iq*4+2)*DD + c;
  float* o3 = gout + (size_t)(i0+iq*4+3)*DD + c;
  atomicAdd(o0+0,acc0.x*inv); atomicAdd(o0+1,acc0.y*inv); atomicAdd(o0+2,acc0.z*inv); atomicAdd(o0+3,acc0.w*inv);
  atomicAdd(o1+0,acc1.x*inv); atomicAdd(o1+1,acc1.y*inv); atomicAdd(o1+2,acc1.z*inv); atomicAdd(o1+3,acc1.w*inv);
  atomicAdd(o2+0,acc2.x*inv); atomicAdd(o2+1,acc2.y*inv); atomicAdd(o2+2,acc2.z*inv); atomicAdd(o2+3,acc2.w*inv);
  atomicAdd(o3+0,acc3.x*inv); atomicAdd(o3+1,acc3.y*inv); atomicAdd(o3+2,acc3.z*inv); atomicAdd(o3+3,acc3.w*inv);
}

__global__ void k_xg(const float* __restrict__ gout, const float* __restrict__ W,
                     const float* __restrict__ b0, float* __restrict__ out){
  int n = blockIdx.x; int j = blockIdx.y*128 + threadIdx.x;
  const float* g = gout + (size_t)n*DD;
  float acc = b0[j];
  for (int k=0;k<128;k++) acc += g[k]*W[(size_t)k*G3 + j];
  out[(size_t)n*G3+j] = acc;
}

/* ---------------- fused bidirectional path GRU (split-bf16 MFMA) ---------------- */
__global__ __launch_bounds__(512) void k_gru2(
    const float* __restrict__ ps_in, float* __restrict__ ps_out,
    const float* __restrict__ xgF, const float* __restrict__ xgB,
    const ushort_t* __restrict__ UthF, const ushort_t* __restrict__ UtlF,
    const ushort_t* __restrict__ UthB, const ushort_t* __restrict__ UtlB,
    const float* __restrict__ b1F, const float* __restrict__ b1B,
    const int* __restrict__ start, const int* __restrict__ lens,
    const int* __restrict__ nodes, const int* __restrict__ perm,
    float* __restrict__ outF, float* __restrict__ outB, int mode)
{
  __shared__ __align__(16) ushort_t HsH[2][32][136];
  __shared__ __align__(16) ushort_t HsL[2][32][136];
  __shared__ int Ls[32], Ss[32], Pid[32];
  __shared__ int nid_l[32][8];

  int dir, pblk;
  if (mode==2){ dir = blockIdx.x & 1; pblk = blockIdx.x >> 1; }
  else        { dir = mode;           pblk = blockIdx.x; }
  const bool rev = (dir==1);
  const float* xg = rev ? xgB : xgF;
  const ushort_t* Uth = rev ? UthB : UthF;
  const ushort_t* Utl = rev ? UtlB : UtlF;
  const float* b1 = rev ? b1B : b1F;
  float* ob = (mode==2) ? (rev ? outB : outF) : outF;
  const bool accum = (mode==1);
  float* psn = rev ? (float*)0 : ps_out;

  int pb = pblk*32;
  int tid = threadIdx.x;
  int w = tid>>6, l = tid&63;
  int lr = l&15, lg = l>>4;
  int c = w*16 + lr;

  if (tid<32){ int pid = perm[pb+tid]; Pid[tid]=pid; Ls[tid]=lens[pid]; Ss[tid]=start[pid]; }
  __syncthreads();
  for (int idx=tid; idx<32*128; idx+=512){
    int pp=idx>>7, kk=idx&127;
    float v = ps_in[(size_t)Pid[pp]*DD+kk];
    ushort_t hi = f2bf(v);
    HsH[0][pp][kk]=hi; HsL[0][pp][kk]=f2bf(v - bf2f(hi));
  }
  if (tid<256){
    int p=tid>>3, s=tid&7; int L=Ls[p];
    int nid = 0;
    if (s<L){ int pos = rev ? (L-1-s) : s; nid = nodes[Ss[p]+pos]; }
    nid_l[p][s]=nid;
  }
  __syncthreads();

  int Lmax = Ls[0];
  int Lv[8], Sv[8];
  #pragma unroll
  for (int i=0;i<8;i++){ int p=(i>>2)*16 + lg*4 + (i&3); Lv[i]=Ls[p]; Sv[i]=Ss[p]; }
  float b1z = b1[c], b1r = b1[128+c], b1h = b1[256+c];

  int cur = 0;
  for (int s=0;s<Lmax;s++){
    int nxt = cur^1;
    bool act[8]; int e_[8]; float xzv[8], xrv[8], xhv[8];
    #pragma unroll
    for (int i=0;i<8;i++){
      int p=(i>>2)*16 + lg*4 + (i&3);
      act[i] = (s < Lv[i]);
      int pos = rev ? (Lv[i]-1-s) : s;
      e_[i] = Sv[i] + pos;
      int nid = nid_l[p][s];
      const float* xr = xg + (size_t)nid*G3;
      xzv[i]=xr[c]; xrv[i]=xr[128+c]; xhv[i]=xr[256+c];
    }
    f4_t accz0=(f4_t)(0.f), accz1=(f4_t)(0.f);
    f4_t accr0=(f4_t)(0.f), accr1=(f4_t)(0.f);
    f4_t acch0=(f4_t)(0.f), acch1=(f4_t)(0.f);
    #pragma unroll
    for (int kt=0; kt<4; kt++){
      int kof = kt*32 + lg*8;
      const bf8_t Ahi0 = *(const bf8_t*)&HsH[cur][lr][kof];
      const bf8_t Alo0 = *(const bf8_t*)&HsL[cur][lr][kof];
      const bf8_t Ahi1 = *(const bf8_t*)&HsH[cur][16+lr][kof];
      const bf8_t Alo1 = *(const bf8_t*)&HsL[cur][16+lr][kof];
      const bf8_t Bhz = *(const bf8_t*)(Uth + ((size_t)(      c))*128 + kof);
      const bf8_t Blz = *(const bf8_t*)(Utl + ((size_t)(      c))*128 + kof);
      const bf8_t Bhr = *(const bf8_t*)(Uth + ((size_t)(128 + c))*128 + kof);
      const bf8_t Blr = *(const bf8_t*)(Utl + ((size_t)(128 + c))*128 + kof);
      const bf8_t Bhh = *(const bf8_t*)(Uth + ((size_t)(256 + c))*128 + kof);
      const bf8_t Blh = *(const bf8_t*)(Utl + ((size_t)(256 + c))*128 + kof);
      accz0 = __builtin_amdgcn_mfma_f32_16x16x32_bf16(Ahi0, Bhz, accz0, 0,0,0);
      accz0 = __builtin_amdgcn_mfma_f32_16x16x32_bf16(Alo0, Bhz, accz0, 0,0,0);
      accz0 = __builtin_amdgcn_mfma_f32_16x16x32_bf16(Ahi0, Blz, accz0, 0,0,0);
      accz1 = __builtin_amdgcn_mfma_f32_16x16x32_bf16(Ahi1, Bhz, accz1, 0,0,0);
      accz1 = __builtin_amdgcn_mfma_f32_16x16x32_bf16(Alo1, Bhz, accz1, 0,0,0);
      accz1 = __builtin_amdgcn_mfma_f32_16x16x32_bf16(Ahi1, Blz, accz1, 0,0,0);
      accr0 = __builtin_amdgcn_mfma_f32_16x16x32_bf16(Ahi0, Bhr, accr0, 0,0,0);
      accr0 = __builtin_amdgcn_mfma_f32_16x16x32_bf16(Alo0, Bhr, accr0, 0,0,0);
      accr0 = __builtin_amdgcn_mfma_f32_16x16x32_bf16(Ahi0, Blr, accr0, 0,0,0);
      accr1 = __builtin_amdgcn_mfma_f32_16x16x32_bf16(Ahi1, Bhr, accr1, 0,0,0);
      accr1 = __builtin_amdgcn_mfma_f32_16x16x32_bf16(Alo1, Bhr, accr1, 0,0,0);
      accr1 = __builtin_amdgcn_mfma_f32_16x16x32_bf16(Ahi1, Blr, accr1, 0,0,0);
      acch0 = __builtin_amdgcn_mfma_f32_16x16x32_bf16(Ahi0, Bhh, acch0, 0,0,0);
      acch0 = __builtin_amdgcn_mfma_f32_16x16x32_bf16(Alo0, Bhh, acch0, 0,0,0);
      acch0 = __builtin_amdgcn_mfma_f32_16x16x32_bf16(Ahi0, Blh, acch0, 0,0,0);
      acch1 = __builtin_amdgcn_mfma_f32_16x16x32_bf16(Ahi1, Bhh, acch1, 0,0,0);
      acch1 = __builtin_amdgcn_mfma_f32_16x16x32_bf16(Alo1, Bhh, acch1, 0,0,0);
      acch1 = __builtin_amdgcn_mfma_f32_16x16x32_bf16(Ahi1, Blh, acch1, 0,0,0);
    }
#define EPI(i, mt, qq, AZ, AR, AH) { \
    int p = (mt)*16 + lg*4 + (qq); \
    if (act[i]) { \
      float hold = bf2f(HsH[cur][p][c]) + bf2f(HsL[cur][p][c]); \
      float z = sigf(xzv[i] + (AZ) + b1z); \
      float r = sigf(xrv[i] + (AR) + b1r); \
      float hc = tanh_fast(xhv[i] + r*((AH) + b1h)); \
      float hn = z*hold + (1.f-z)*hc; \
      ushort_t hi2 = f2bf(hn); \
      HsH[nxt][p][c]=hi2; HsL[nxt][p][c]=f2bf(hn - bf2f(hi2)); \
      float* o = ob + (size_t)e_[i]*DD + c; \
      if (accum) *o += hn; else *o = hn; \
    } else { \
      HsH[nxt][p][c]=HsH[cur][p][c]; HsL[nxt][p][c]=HsL[cur][p][c]; \
    } }
    EPI(0,0,0, accz0.x, accr0.x, acch0.x)
    EPI(1,0,1, accz0.y, accr0.y, acch0.y)
    EPI(2,0,2, accz0.z, accr0.z, acch0.z)
    EPI(3,0,3, accz0.w, accr0.w, acch0.w)
    EPI(4,1,0, accz1.x, accr1.x, acch1.x)
    EPI(5,1,1, accz1.y, accr1.y, acch1.y)
    EPI(6,1,2, accz1.z, accr1.z, acch1.z)
    EPI(7,1,3, accz1.w, accr1.w, acch1.w)
#undef EPI
    __syncthreads();
    cur = nxt;
  }
  if (psn){
    for (int idx=tid; idx<32*128; idx+=512){
      int pp=idx>>7, kk=idx&127;
      psn[(size_t)Pid[pp]*DD+kk] = bf2f(HsH[cur][pp][kk]) + bf2f(HsL[cur][pp][kk]);
    }
  }
}

/* ---------------- m2 + node GRU ---------------- */
__global__ void k_m2(const float* __restrict__ outF, const float* __restrict__ outB,
                     const int* __restrict__ counts,
                     const int* __restrict__ offsets, const int* __restrict__ bucket,
                     float* __restrict__ m2){
  int n = blockIdx.x; int c = threadIdx.x; /* 128 threads */
  int cnt = counts[n], off = offsets[n];
  float acc = 0.f;
  if (outB){
    for (int idx=0; idx<cnt; ++idx){
      int e = bucket[off+idx];
      acc += outF[(size_t)e*DD + c] + outB[(size_t)e*DD + c];
    }
  } else {
    for (int idx=0; idx<cnt; ++idx){
      int e = bucket[off+idx];
      acc += outF[(size_t)e*DD + c];
    }
  }
  m2[n*DD+c] = acc;
}

__global__ void k_ngru(const float* __restrict__ m2, const float* __restrict__ gout,
                       const float* __restrict__ Wn, const float* __restrict__ Un,
                       const float* __restrict__ bn, float* __restrict__ ns){
  int n = blockIdx.x, c = threadIdx.x; /* 128 threads */
  float xz=0.f,xr=0.f,xh=0.f,hz=0.f,hr=0.f,hh=0.f;
  const float* x = m2 + (size_t)n*DD; const float* h = gout + (size_t)n*DD;
  for (int k=0;k<128;k++){
    float xk=x[k], hk=h[k];
    const float* wr = Wn + (size_t)k*G3; const float* ur = Un + (size_t)k*G3;
    xz += xk*wr[c]; xr += xk*wr[128+c]; xh += xk*wr[256+c];
    hz += hk*ur[c]; hr += hk*ur[128+c]; hh += hk*ur[256+c];
  }
  float z = sigf(xz+bn[c]     + hz+bn[G3+c]);
  float r = sigf(xr+bn[128+c] + hr+bn[G3+128+c]);
  float hc = tanh_fast(xh+bn[256+c] + r*(hh+bn[G3+256+c]));
  ns[n*DD+c] = z*h[c] + (1.f-z)*hc;
}

/* ---------------- MFMA readout ---------------- */
__global__ __launch_bounds__(512) void k_read2(
    const float* __restrict__ ps,
    const ushort_t* __restrict__ r1h, const ushort_t* __restrict__ r1l,
    const ushort_t* __restrict__ r2h, const ushort_t* __restrict__ r2l,
    const float* __restrict__ rb1, const float* __restrict__ rb2,
    const float* __restrict__ rW3, const float* __restrict__ rb3,
    float* __restrict__ out)
{
  __shared__ __align__(16) ushort_t XsH[32][136], XsL[32][136];
  __shared__ __align__(16) char buf[32*264*2*2];
  ushort_t (*H1H)[264] = (ushort_t(*)[264])buf;
  ushort_t (*H1L)[264] = (ushort_t(*)[264])(buf + 32*264*2);
  float (*H2)[257] = (float(*)[257])buf;
  int pb = blockIdx.x*32, tid = threadIdx.x;
  int w = tid>>6, l = tid&63, lr = l&15, lg = l>>4;
  for (int idx=tid; idx<32*128; idx+=512){
    int pp=idx>>7, kk=idx&127;
    float v = ps[(size_t)(pb+pp)*DD+kk];
    ushort_t hi=f2bf(v); XsH[pp][kk]=hi; XsL[pp][kk]=f2bf(v-bf2f(hi));
  }
  __syncthreads();
  int col0 = w*32 + lr, col1 = col0 + 16;
  f4_t a00=(f4_t)(0.f), a01=(f4_t)(0.f), a10=(f4_t)(0.f), a11=(f4_t)(0.f);
  #pragma unroll
  for (int kt=0; kt<4; kt++){
    int kof = kt*32 + lg*8;
    const bf8_t Ah0 = *(const bf8_t*)&XsH[lr][kof];
    const bf8_t Al0 = *(const bf8_t*)&XsL[lr][kof];
    const bf8_t Ah1 = *(const bf8_t*)&XsH[16+lr][kof];
    const bf8_t Al1 = *(const bf8_t*)&XsL[16+lr][kof];
    const bf8_t B0h = *(const bf8_t*)(r1h + (size_t)col0*128 + kof);
    const bf8_t B0l = *(const bf8_t*)(r1l + (size_t)col0*128 + kof);
    const bf8_t B1h = *(const bf8_t*)(r1h + (size_t)col1*128 + kof);
    const bf8_t B1l = *(const bf8_t*)(r1l + (size_t)col1*128 + kof);
    a00 = __builtin_amdgcn_mfma_f32_16x16x32_bf16(Ah0,B0h,a00,0,0,0);
    a00 = __builtin_amdgcn_mfma_f32_16x16x32_bf16(Al0,B0h,a00,0,0,0);
    a00 = __builtin_amdgcn_mfma_f32_16x16x32_bf16(Ah0,B0l,a00,0,0,0);
    a01 = __builtin_amdgcn_mfma_f32_16x16x32_bf16(Ah0,B1h,a01,0,0,0);
    a01 = __builtin_amdgcn_mfma_f32_16x16x32_bf16(Al0,B1h,a01,0,0,0);
    a01 = __builtin_amdgcn_mfma_f32_16x16x32_bf16(Ah0,B1l,a01,0,0,0);
    a10 = __builtin_amdgcn_mfma_f32_16x16x32_bf16(Ah1,B0h,a10,0,0,0);
    a10 = __builtin_amdgcn_mfma_f32_16x16x32_bf16(Al1,B0h,a10,0,0,0);
    a10 = __builtin_amdgcn_mfma_f32_16x16x32_bf16(Ah1,B0l,a10,0,0,0);
    a11 = __builtin_amdgcn_mfma_f32_16x16x32_bf16(Ah1,B1h,a11,0,0,0);
    a11 = __builtin_amdgcn_mfma_f32_16x16x32_bf16(Al1,B1h,a11,0,0,0);
    a11 = __builtin_amdgcn_mfma_f32_16x16x32_bf16(Ah1,B1l,a11,0,0,0);
  }
  float rb1c0 = rb1[col0], rb1c1 = rb1[col1];
  #pragma unroll
  for (int q=0;q<4;q++){
    int row0 = lg*4+q, row1 = 16+lg*4+q;
    float v00 = a00[q]+rb1c0, v01 = a01[q]+rb1c1, v10 = a10[q]+rb1c0, v11 = a11[q]+rb1c1;
    v00 = 1.0507009873554805f * (v00>0.f ? v00 : 1.6732632423543772f*(__expf(v00)-1.f));
    v01 = 1.0507009873554805f * (v01>0.f ? v01 : 1.6732632423543772f*(__expf(v01)-1.f));
    v10 = 1.0507009873554805f * (v10>0.f ? v10 : 1.6732632423543772f*(__expf(v10)-1.f));
    v11 = 1.0507009873554805f * (v11>0.f ? v11 : 1.6732632423543772f*(__expf(v11)-1.f));
    ushort_t h;
    h=f2bf(v00); H1H[row0][col0]=h; H1L[row0][col0]=f2bf(v00-bf2f(h));
    h=f2bf(v01); H1H[row0][col1]=h; H1L[row0][col1]=f2bf(v01-bf2f(h));
    h=f2bf(v10); H1H[row1][col0]=h; H1L[row1][col0]=f2bf(v10-bf2f(h));
    h=f2bf(v11); H1H[row1][col1]=h; H1L[row1][col1]=f2bf(v11-bf2f(h));
  }
  __syncthreads();
  f4_t c00=(f4_t)(0.f), c01=(f4_t)(0.f), c10=(f4_t)(0.f), c11=(f4_t)(0.f);
  #pragma unroll
  for (int kt=0; kt<8; kt++){
    int kof = kt*32 + lg*8;
    const bf8_t Ah0 = *(const bf8_t*)&H1H[lr][kof];
    const bf8_t Al0 = *(const bf8_t*)&H1L[lr][kof];
    const bf8_t Ah1 = *(const bf8_t*)&H1H[16+lr][kof];
    const bf8_t Al1 = *(const bf8_t*)&H1L[16+lr][kof];
    const bf8_t B0h = *(const bf8_t*)(r2h + (size_t)col0*256 + kof);
    const bf8_t B0l = *(const bf8_t*)(r2l + (size_t)col0*256 + kof);
    const bf8_t B1h = *(const bf8_t*)(r2h + (size_t)col1*256 + kof);
    const bf8_t B1l = *(const bf8_t*)(r2l + (size_t)col1*256 + kof);
    c00 = __builtin_amdgcn_mfma_f32_16x16x32_bf16(Ah0,B0h,c00,0,0,0);
    c00 = __builtin_amdgcn_mfma_f32_16x16x32_bf16(Al0,B0h,c00,0,0,0);
    c00 = __builtin_amdgcn_mfma_f32_16x16x32_bf16(Ah0,B0l,c00,0,0,0);
    c01 = __builtin_amdgcn_mfma_f32_16x16x32_bf16(Ah0,B1h,c01,0,0,0);
    c01 = __builtin_amdgcn_mfma_f32_16x16x32_bf16(Al0,B1h,c01,0,0,0);
    c01 = __builtin_amdgcn_mfma_f32_16x16x32_bf16(Ah0,B1l,c01,0,0,0);
    c10 = __builtin_amdgcn_mfma_f32_16x16x32_bf16(Ah1,B0h,c10,0,0,0);
    c10 = __builtin_amdgcn_mfma_f32_16x16x32_bf16(Al1,B0h,c10,0,0,0);
    c10 = __builtin_amdgcn_mfma_f32_16x16x32_bf16(Ah1,B0l,c10,0,0,0);
    c11 = __builtin_amdgcn_mfma_f32_16x16x32_bf16(Ah1,B1h,c11,0,0,0);
    c11 = __builtin_amdgcn_mfma_f32_16x16x32_bf16(Al1,B1h,c11,0,0,0);
    c11 = __builtin_amdgcn_mfma_f32_16x16x32_bf16(Ah1,B1l,c11,0,0,0);
  }
  __syncthreads();
  float rb2c0 = rb2[col0], rb2c1 = rb2[col1];
  #pragma unroll
  for (int q=0;q<4;q++){
    int row0 = lg*4+q, row1 = 16+lg*4+q;
    H2[row0][col0] = fmaxf(c00[q]+rb2c0, 0.f);
    H2[row0][col1] = fmaxf(c01[q]+rb2c1, 0.f);
    H2[row1][col0] = fmaxf(c10[q]+rb2c0, 0.f);
    H2[row1][col1] = fmaxf(c11[q]+rb2c1, 0.f);
  }
  __syncthreads();
  int r = tid>>4, j0 = tid&15;
  float s = 0.f;
  for (int j=j0; j<256; j+=16) s += H2[r][j]*rW3[j];
  for (int o=8;o>0;o>>=1) s += __shfl_xor(s,o);
  if (j0==0) out[pb+r] = s + rb3[0];
}

/* ---------------- host ---------------- */
extern "C" void kernel_launch(void* const* d_in, const int* in_sizes, int n_in,
                              void* d_out, int out_size, void* d_ws, size_t ws_size,
                              hipStream_t stream)
{
  const float* ToS   = (const float*)d_in[0];
  const float* bw    = (const float*)d_in[1];
  const float* qpol  = (const float*)d_in[2];
  const float* w1    = (const float*)d_in[3];
  const float* w2    = (const float*)d_in[4];
  const float* w3    = (const float*)d_in[5];
  const float* qs    = (const float*)d_in[6];
  const float* lc    = (const float*)d_in[7];
  const float* gat_W = (const float*)d_in[8];
  const float* gat_as= (const float*)d_in[9];
  const float* gat_an= (const float*)d_in[10];
  const float* gat_b = (const float*)d_in[11];
  const float* Wp    = (const float*)d_in[12];
  const float* Up    = (const float*)d_in[13];
  const float* bp    = (const float*)d_in[14];
  const float* Wb    = (const float*)d_in[15];
  const float* Ub    = (const float*)d_in[16];
  const float* bb    = (const float*)d_in[17];
  const float* Wn    = (const float*)d_in[18];
  const float* Un    = (const float*)d_in[19];
  const float* bn    = (const float*)d_in[20];
  const float* rW1   = (const float*)d_in[21];
  const float* rb1   = (const float*)d_in[22];
  const float* rW2   = (const float*)d_in[23];
  const float* rb2   = (const float*)d_in[24];
  const float* rW3   = (const float*)d_in[25];
  const float* rb3   = (const float*)d_in[26];
  const int* paths   = (const int*)d_in[27];
  const int* seqs    = (const int*)d_in[28];
  const int* nodes   = (const int*)d_in[29];
  const int* adj_idx = (const int*)d_in[30];
  int E = in_sizes[27];

  char* w0 = (char*)d_ws;
  char* w = w0;
  auto alloc = [&](size_t nbytes)->void*{ void* r=(void*)w; w += (nbytes + 255) & ~(size_t)255; return r; };
  float* ns     = (float*)alloc((size_t)NN*DD*4);
  float* gout   = (float*)alloc((size_t)NN*DD*4);
  float* psA    = (float*)alloc((size_t)NP*DD*4);
  float* psB    = (float*)alloc((size_t)NP*DD*4);
  float* xp     = (float*)alloc((size_t)NN*NHD*4);
  float* es     = (float*)alloc((size_t)NN*NH*4);
  float* en     = (float*)alloc((size_t)NN*NH*4);
  unsigned int* adjb = (unsigned int*)alloc((size_t)NN*16*4);
  float* xgp    = (float*)alloc((size_t)NN*G3*4);
  float* xgb    = (float*)alloc((size_t)NN*G3*4);
  float* m2     = (float*)alloc((size_t)NN*DD*4);
  unsigned short* Uthp = (unsigned short*)alloc((size_t)G3*DD*2);
  unsigned short* Utlp = (unsigned short*)alloc((size_t)G3*DD*2);
  unsigned short* Uthb = (unsigned short*)alloc((size_t)G3*DD*2);
  unsigned short* Utlb = (unsigned short*)alloc((size_t)G3*DD*2);
  ushort_t* r1h = (ushort_t*)alloc((size_t)256*128*2);
  ushort_t* r1l = (ushort_t*)alloc((size_t)256*128*2);
  ushort_t* r2h = (ushort_t*)alloc((size_t)256*256*2);
  ushort_t* r2l = (ushort_t*)alloc((size_t)256*256*2);
  ushort_t* gwh = (ushort_t*)alloc((size_t)NHD*DD*2);
  ushort_t* gwl = (ushort_t*)alloc((size_t)NHD*DD*2);
  int* start    = (int*)alloc((size_t)NP*4);
  int* lens     = (int*)alloc((size_t)NP*4);
  int* counts   = (int*)alloc((size_t)NN*4);
  int* offsets  = (int*)alloc((size_t)NN*4);
  int* cursor   = (int*)alloc((size_t)NN*4);
  int* perm     = (int*)alloc((size_t)NP*4);
  int* lcnt     = (int*)alloc(16*4);
  int* loff     = (int*)alloc(16*4);
  int* lcur     = (int*)alloc(16*4);
  int* bucket   = (int*)alloc((size_t)E*4);
  float* outF   = (float*)alloc((size_t)E*DD*4);
  char* w_no_outB = w;
  float* outB   = (float*)alloc((size_t)E*DD*4);
  bool fused = ((size_t)(w - w0) <= ws_size);
  if (!fused){ outB = nullptr; w = w_no_outB; }
  (void)n_in; (void)out_size;

  hipMemsetAsync(adjb, 0, (size_t)NN*16*4, stream);
  hipMemsetAsync(counts, 0, (size_t)NN*4, stream);
  hipMemsetAsync(lcnt, 0, 16*4, stream);
  k_init_ns<<<NN,DD,0,stream>>>(ns, qpol, w1, w2, w3, qs);
  k_init_ps<<<(NP*DD+255)/256,256,0,stream>>>(psA, bw, ToS);
  k_adj<<<16,256,0,stream>>>(adjb, adj_idx, lc);
  k_meta<<<(E+255)/256,256,0,stream>>>(paths, seqs, start, lens, E);
  k_count<<<(E+255)/256,256,0,stream>>>(nodes, counts, E);
  k_scan<<<1,NN,0,stream>>>(counts, offsets, cursor);
  k_fill<<<(E+255)/256,256,0,stream>>>(nodes, cursor, bucket, E);
  k_lcount<<<(NP+255)/256,256,0,stream>>>(lens, lcnt);
  k_lscan<<<1,64,0,stream>>>(lcnt, loff, lcur);
  k_lfill<<<(NP+255)/256,256,0,stream>>>(lens, lcur, perm);
  k_ut<<<(G3*DD+255)/256,256,0,stream>>>(Up, Uthp, Utlp);
  k_ut<<<(G3*DD+255)/256,256,0,stream>>>(Ub, Uthb, Utlb);
  k_wsplit<<<(256*128+255)/256,256,0,stream>>>(rW1, r1h, r1l, 7, 256, 256*128);
  k_wsplit<<<(256*256+255)/256,256,0,stream>>>(rW2, r2h, r2l, 8, 256, 256*256);
  k_wsplit<<<(NHD*DD+255)/256,256,0,stream>>>(gat_W, gwh, gwl, 7, NHD, NHD*DD);

  float* ps_cur = psA; float* ps_nxt = psB;
  for (int t=0;t<3;t++){
    k_xp2<<<dim3(NN/32, NHD/256),512,0,stream>>>(ns, gwh, gwl, xp);
    k_gat_e<<<dim3(NN,NH),64,0,stream>>>(xp, gat_as, gat_an, es, en);
    k_gat_bias<<<NN,DD,0,stream>>>(gout, gat_b);
    k_attn<<<dim3(NH, NN/32),256,0,stream>>>(xp, es, en, adjb, gout);
    k_xg<<<dim3(NN,3),128,0,stream>>>(gout, Wp, bp, xgp);
    k_xg<<<dim3(NN,3),128,0,stream>>>(gout, Wb, bb, xgb);
    if (fused){
      k_gru2<<<2*(NP/32),512,0,stream>>>(ps_cur, ps_nxt, xgp, xgb, Uthp, Utlp, Uthb, Utlb,
                                         bp+G3, bb+G3, start, lens, nodes, perm, outF, outB, 2);
    } else {
      k_gru2<<<NP/32,512,0,stream>>>(ps_cur, ps_nxt, xgp, xgb, Uthp, Utlp, Uthb, Utlb,
                                     bp+G3, bb+G3, start, lens, nodes, perm, outF, nullptr, 0);
      k_gru2<<<NP/32,512,0,stream>>>(ps_cur, nullptr, xgp, xgb, Uthp, Utlp, Uthb, Utlb,
                                     bp+G3, bb+G3, start, lens, nodes, perm, outF, nullptr, 1);
    }
    k_m2<<<NN,DD,0,stream>>>(outF, outB, counts, offsets, bucket, m2);
    k_ngru<<<NN,DD,0,stream>>>(m2, gout, Wn, Un, bn, ns);
    float* tmp = ps_cur; ps_cur = ps_nxt; ps_nxt = tmp;
  }
  k_read2<<<NP/32,512,0,stream>>>(ps_cur, r1h, r1l, r2h, r2l, rb1, rb2, rW3, rb3, (float*)d_out);
}